// Round 5
// baseline (2752.932 us; speedup 1.0000x reference)
//
#include <hip/hip_runtime.h>

#define BD 256   // batch
#define HD 1024  // hidden
#define KC 2048  // concatenated K = [x | h]
#define LATD 512 // latent
#define OD 128   // output dim
#define TS 100   // seq_len (fixed by problem)

typedef __attribute__((ext_vector_type(8))) short s16x8;
typedef __attribute__((ext_vector_type(4))) float f32x4;

__device__ __forceinline__ float b2f(short s) {
  return __uint_as_float(((unsigned)(unsigned short)s) << 16);
}
__device__ __forceinline__ short f2b(float f) {
  unsigned u = __float_as_uint(f);
  u += 0x7fff + ((u >> 16) & 1);  // RNE
  return (short)(u >> 16);
}
__device__ __forceinline__ float sigm(float x) { return 1.f / (1.f + __expf(-x)); }
__device__ __forceinline__ float tanh_f(float x) { return 1.f - 2.f / (__expf(2.f * x) + 1.f); }

// h-only fragment-major index over kh in [0,1024):
// kc=kh/8, q2=kc/64 (h-quarter), it=(kc/4)%16, qq=kc%4; mt=m/16, r=m%16
// frag (mt,q2,it) base = (mt*32 + q2*16 + it)*512 shorts; lane entry qq*16+r at *8
__device__ __forceinline__ size_t hf_idx(int m, int kh) {
  int kc = kh >> 3;
  int q2 = kc >> 6, it = (kc >> 2) & 15, qq = kc & 3;
  int mt = m >> 4, r = m & 15;
  return (((size_t)(mt * 32 + q2 * 16 + it)) * 64 + qq * 16 + r) * 8 + (kh & 7);
}

// relu on bf16 == signed 16-bit max(s,0) (exact; -0 -> +0)
__device__ __forceinline__ s16x8 relu8(s16x8 v) {
  s16x8 o;
#pragma unroll
  for (int e = 0; e < 8; ++e) o[e] = v[e] > 0 ? v[e] : (short)0;
  return o;
}

// ---------------- one-time prep kernels ----------------

__global__ __launch_bounds__(256) void cvt8_k(const float* __restrict__ in,
                                              short* __restrict__ out) {
  int i = (blockIdx.x * 256 + threadIdx.x) * 8;
  f32x4 a = *(const f32x4*)(in + i), b = *(const f32x4*)(in + i + 4);
  s16x8 o;
#pragma unroll
  for (int e = 0; e < 4; ++e) { o[e] = f2b(a[e]); o[4 + e] = f2b(b[e]); }
  *(s16x8*)(out + i) = o;
}

// Fragment-major weight repack (verified r6):
// chunk i = ((bn*64 + kit)*4 + quad)*16 + lan; bn = g*64+bx; k = kit*32+quad*8
__global__ __launch_bounds__(256) void wrep_k(const float* __restrict__ Wih,
                                              const float* __restrict__ Whh,
                                              short* __restrict__ Wt) {
  int i = blockIdx.x * 256 + threadIdx.x;  // chunk id, < 1048576
  int lan = i & 15, quad = (i >> 4) & 3, kit = (i >> 6) & 63, bn = i >> 12;
  int g = bn >> 6, bx = bn & 63;
  int n = g * HD + bx * 16 + lan;
  int k = kit * 32 + quad * 8;
  const float* src = (k < HD) ? (Wih + (size_t)n * HD + k)
                              : (Whh + (size_t)n * HD + (k - HD));
  f32x4 a = *(const f32x4*)src, b = *(const f32x4*)(src + 4);
  s16x8 o;
#pragma unroll
  for (int e = 0; e < 4; ++e) { o[e] = f2b(a[e]); o[4 + e] = f2b(b[e]); }
  *(s16x8*)(Wt + (size_t)i * 8) = o;
}

__global__ __launch_bounds__(256) void bsum_k(const float* __restrict__ bi,
                                              const float* __restrict__ bh,
                                              float* __restrict__ bs) {
  int i = blockIdx.x * 256 + threadIdx.x;
  bs[i] = bi[i] + bh[i];
}

__global__ __launch_bounds__(256) void x0_k(const float* __restrict__ st,
                                            const float* __restrict__ W,
                                            const float* __restrict__ bias,
                                            short* __restrict__ xrow) {
  int j = blockIdx.x * 256 + threadIdx.x;
  float acc = 0.f;
  for (int k = 0; k < OD; ++k) acc += st[k] * W[j * OD + k];
  acc += bias[j];
  xrow[j] = f2b(acc > 0.f ? acc : 0.f);
}

// xg[j] = sum_k relu(x0)[k] * Wih[j][k]  (step-0 x-contribution, batch-invariant)
__global__ __launch_bounds__(256) void xg_k(const short* __restrict__ xrow,
                                            const float* __restrict__ Wih,
                                            float* __restrict__ xg) {
  int l = threadIdx.x & 63, w = threadIdx.x >> 6;
  int j = blockIdx.x * 4 + w;  // 1024 blocks -> j < 4096
  const float* row = Wih + (size_t)j * HD + l * 16;
  float acc = 0.f;
#pragma unroll
  for (int c = 0; c < 16; ++c) acc += b2f(xrow[l * 16 + c]) * row[c];
  for (int off = 32; off; off >>= 1) acc += __shfl_down(acc, off);
  if (l == 0) xg[j] = acc;
}

__global__ void zero_ctr_k(unsigned* __restrict__ c) { c[threadIdx.x] = 0u; }

// ---------------- head GEMM: out = lrelu(A @ W^T + b), N=1024, M=256 ----------------
// MODE: 0 = fp32 flat [m*1024+col]; 1 = bf16 flat [m*os+oo+col]; 2 = bf16 hf layout
template <int K, bool IN_BF16, int MODE>
__global__ __launch_bounds__(256) void fc_mfma(const void* __restrict__ in_,
                                               const float* __restrict__ W,
                                               const float* __restrict__ bias,
                                               void* __restrict__ out_,
                                               int ostride, int ooff) {
  const int tid = threadIdx.x;
  const int w = tid >> 6, lan = tid & 15, quad = (tid & 63) >> 4;
  const int n0 = blockIdx.x * 64;
  const int m0 = blockIdx.y * 64;
  const int arow = m0 + w * 16 + lan;
  f32x4 acc[4] = {};
  for (int k0 = 0; k0 < K; k0 += 32) {
    const int ka = k0 + quad * 8;
    s16x8 af;
    if (IN_BF16) {
      af = *(const s16x8*)((const short*)in_ + arow * K + ka);
    } else {
      const float* ap = (const float*)in_ + arow * K + ka;
      f32x4 a0 = *(const f32x4*)ap, a1 = *(const f32x4*)(ap + 4);
#pragma unroll
      for (int e = 0; e < 4; ++e) { af[e] = f2b(a0[e]); af[4 + e] = f2b(a1[e]); }
    }
#pragma unroll
    for (int nf = 0; nf < 4; ++nf) {
      const float* bp = W + (n0 + nf * 16 + lan) * K + ka;
      f32x4 b0 = *(const f32x4*)bp, b1 = *(const f32x4*)(bp + 4);
      s16x8 bf;
#pragma unroll
      for (int e = 0; e < 4; ++e) { bf[e] = f2b(b0[e]); bf[4 + e] = f2b(b1[e]); }
      acc[nf] = __builtin_amdgcn_mfma_f32_16x16x32_bf16(af, bf, acc[nf], 0, 0, 0);
    }
  }
#pragma unroll
  for (int nf = 0; nf < 4; ++nf) {
    int col = n0 + nf * 16 + lan;
    float bb = bias[col];
#pragma unroll
    for (int j = 0; j < 4; ++j) {
      int m = m0 + w * 16 + quad * 4 + j;
      float v = acc[nf][j] + bb;
      v = v > 0.f ? v : 0.01f * v;
      if (MODE == 0)
        ((float*)out_)[m * 1024 + col] = v;
      else if (MODE == 1)
        ((short*)out_)[m * ostride + ooff + col] = f2b(v);
      else
        ((short*)out_)[hf_idx(m, col)] = f2b(v);
    }
  }
}

__global__ __launch_bounds__(256) void num_k(const float* __restrict__ n1,
                                             const float* __restrict__ w2,
                                             const float* __restrict__ b2,
                                             float* __restrict__ out) {
  int l = threadIdx.x & 63, w = threadIdx.x >> 6;
  int m = blockIdx.x * 4 + w;
  const float* r = n1 + m * HD + l * 16;
  const float* wv = w2 + l * 16;
  float acc = 0.f;
#pragma unroll
  for (int c = 0; c < 4; ++c) {
    f32x4 a = *(const f32x4*)(r + c * 4), b = *(const f32x4*)(wv + c * 4);
#pragma unroll
    for (int e = 0; e < 4; ++e) acc += a[e] * b[e];
  }
  for (int off = 32; off; off >>= 1) acc += __shfl_down(acc, off);
  if (l == 0) {
    float v = acc + b2[0];
    out[m] = v > 0.f ? v : 0.f;
  }
}

__global__ __launch_bounds__(256) void mass_k(const short* __restrict__ m2,
                                              const float* __restrict__ w3,
                                              const float* __restrict__ b3,
                                              float* __restrict__ out) {
  int l = threadIdx.x & 63, w = threadIdx.x >> 6;
  int m = blockIdx.x * 4 + w;
  const short* r = m2 + m * HD + l * 16;
  s16x8 v0 = *(const s16x8*)r, v1 = *(const s16x8*)(r + 8);
  float z0 = 0.f, z1 = 0.f;
#pragma unroll
  for (int e = 0; e < 8; ++e) {
    float a = b2f(v0[e]), b = b2f(v1[e]);
    z0 += a * w3[l * 16 + e] + b * w3[l * 16 + 8 + e];
    z1 += a * w3[HD + l * 16 + e] + b * w3[HD + l * 16 + 8 + e];
  }
  for (int off = 32; off; off >>= 1) {
    z0 += __shfl_down(z0, off);
    z1 += __shfl_down(z1, off);
  }
  if (l == 0) {
    z0 += b3[0]; z1 += b3[1];
    float mx = fmaxf(z0, z1);
    float e0 = __expf(z0 - mx), e1 = __expf(z1 - mx);
    float s = e0 + e1;
    out[m * 2] = e0 / s;
    out[m * 2 + 1] = e1 / s;
  }
}

// ---------------- persistent LSTM kernel ----------------
// Grid (64,4), 512 threads (8 waves), one block/CU (128 KB LDS forces it).
// Weights pinned in VGPRs. Per step only h (128 KB/block) is staged.
// KEY (R5): h staging loads are sc0-only (L1-bypass, L2-CACHEABLE) so the 64x
// broadcast within a by-group is served by each XCD's L2 instead of hammering
// L3 (R4 was L3-BW-bound at ~12 us/step). Stale L2 lines are dropped by an
// agent acquire fence (buffer_inv sc1) at the top of every step. To make the
// inv safe, EVERY global store in this kernel is write-through agent-scope
// (h, hsC, dout, o_h, o_c) -> L2 never holds dirty data here.

#define MF(a, b, c) __builtin_amdgcn_mfma_f32_16x16x32_bf16(a, b, c, 0, 0, 0)

typedef __attribute__((address_space(1))) const void gas_void;
typedef __attribute__((address_space(3))) void las_void;

// single-hop barrier: one agent store per block; wave 0 polls all 64 slots.
__device__ __forceinline__ void grid_bar(unsigned* slots, unsigned epoch, int bx) {
  asm volatile("s_waitcnt vmcnt(0)" ::: "memory");  // all sc1 stores acked at L3
  __syncthreads();
  if (threadIdx.x == 0)
    __hip_atomic_store(slots + bx, epoch, __ATOMIC_RELAXED, __HIP_MEMORY_SCOPE_AGENT);
  if (threadIdx.x < 64) {
    while (!__all(__hip_atomic_load(slots + (int)threadIdx.x, __ATOMIC_RELAXED,
                                    __HIP_MEMORY_SCOPE_AGENT) >= epoch))
      __builtin_amdgcn_s_sleep(1);
  }
  __syncthreads();
}

__global__ __launch_bounds__(512, 2) void lstm_persist(
    short* __restrict__ hA, short* __restrict__ hB, const float* __restrict__ cbuf,
    const short* __restrict__ Wt, const float* __restrict__ bsum,
    const float* __restrict__ xg, short* __restrict__ hsC,
    const short* __restrict__ outw, const float* __restrict__ outb,
    float* __restrict__ dout, float* __restrict__ o_h, float* __restrict__ o_c,
    unsigned* ctr, int CH) {
  __shared__ __align__(16) short sm[65536];  // 2 x 64 KB h-quarter buffers; red reuses [0,64K)

  const int tid = threadIdx.x;
  const int w = tid >> 6, l = tid & 63;
  const int w4 = w & 3, gp = w >> 2;   // wave = (K-quarter, gate-pair)
  const int bx = blockIdx.x, by = blockIdx.y;
  const int q = l >> 4, r = l & 15;
  const int q2 = w4 & 1;               // h-quarter this wave consumes
  const int sr = (w4 >> 1) + 2 * gp;   // stager rank within quarter [0,4)

  // ---- one-time weight preload: kq = w4, 32 frags = 128 VGPR/thread ----
  s16x8 W[32];
#pragma unroll
  for (int it = 0; it < 16; ++it)
#pragma unroll
    for (int gi = 0; gi < 2; ++gi) {
      const int g = gp * 2 + gi;
      W[it * 2 + gi] =
          *(const s16x8*)(Wt + (((size_t)(g * 64 + bx) * 64 + w4 * 16 + it) * 64 + l) * 8);
    }
  // pin: opaque to the register allocator -> no remat/re-stream from L2
#pragma unroll
  for (int i = 0; i < 32; ++i) asm volatile("" : "+v"(W[i]));

  // ---- per-thread epilogue constants ----
  const int mloc0 = tid >> 4, hc = tid & 15;
  const int chh = bx * 16 + hc;
  const float bs0 = bsum[chh], bs1 = bsum[HD + chh];
  const float bs2 = bsum[2 * HD + chh], bs3 = bsum[3 * HD + chh];
  const float xg0 = xg[chh], xg1 = xg[HD + chh];
  const float xg2 = xg[2 * HD + chh], xg3 = xg[3 * HD + chh];
  int idxA[2];
  size_t hIdx[2];
  float creg[2];
#pragma unroll
  for (int cc2 = 0; cc2 < 2; ++cc2) {
    const int mg = by * 64 + mloc0 + cc2 * 32;
    idxA[cc2] = mg * HD + chh;
    hIdx[cc2] = hf_idx(mg, chh);
    creg[cc2] = cbuf[idxA[cc2]];  // c-state in registers for all 100 steps
  }

  float* red = (float*)sm;
  unsigned* s1 = ctr + by * 128;
  unsigned* s2 = s1 + 64;
  int tslot = 0;
  unsigned pcnt = 0;

  for (int t = 0; t < TS; ++t) {
    const short* src = (t & 1) ? hB : hA;
    short* dst = (t & 1) ? hA : hB;

    // drop stale L2 lines (peers' h(t) was written sc1 -> L3 only).
    // Safe: no dirty L2 data exists in this kernel (all stores write-through).
    __builtin_amdgcn_fence(__ATOMIC_ACQUIRE, "agent");

    f32x4 c00 = {}, c01 = {}, c10 = {}, c11 = {};
    f32x4 c20 = {}, c21 = {}, c30 = {}, c31 = {};

    // ---- stage this wave's 16 frags of h-quarter q2 (sc0: L1-bypass, L2-cache) ----
#pragma unroll
    for (int j = 0; j < 16; ++j) {
      const int fi = sr * 16 + j;            // it = fi>>2, mtl = fi&3
      const int it = fi >> 2, mtl = fi & 3;
      const short* g = src + ((size_t)((by * 4 + mtl) * 32 + q2 * 16 + it)) * 512 + (size_t)l * 8;
      __builtin_amdgcn_global_load_lds((gas_void*)g,
                                       (las_void*)(sm + q2 * 32768 + fi * 512), 16, 0, 1);
    }
    asm volatile("s_waitcnt vmcnt(0)" ::: "memory");
    __builtin_amdgcn_s_barrier();

    // ---- 128 MFMA/wave on own quarter; x-waves apply in-register relu ----
    if (t > 0 || w4 >= 2) {
      const short* cb = sm + q2 * 32768;
#pragma unroll
      for (int it = 0; it < 16; ++it) {
        const short* fb = cb + it * 2048 + l * 8;
        s16x8 a0 = *(const s16x8*)(fb);
        s16x8 a1 = *(const s16x8*)(fb + 512);
        s16x8 a2 = *(const s16x8*)(fb + 1024);
        s16x8 a3 = *(const s16x8*)(fb + 1536);
        if (w4 < 2) { a0 = relu8(a0); a1 = relu8(a1); a2 = relu8(a2); a3 = relu8(a3); }
        const s16x8 w0 = W[it * 2], w1 = W[it * 2 + 1];
        c00 = MF(a0, w0, c00); c01 = MF(a0, w1, c01);
        c10 = MF(a1, w0, c10); c11 = MF(a1, w1, c11);
        c20 = MF(a2, w0, c20); c21 = MF(a2, w1, c21);
        c30 = MF(a3, w0, c30); c31 = MF(a3, w1, c31);
      }
    }
    __builtin_amdgcn_s_barrier();  // all LDS reads done before red overwrites [0,64K)

    // ---- partials to LDS: slot s = mtl*2+gi at float ((s*512 + w*64 + l)*4) ----
    {
      float* base = red + (size_t)(w * 64 + l) * 4;
      *(f32x4*)(base + 0 * 2048) = c00;
      *(f32x4*)(base + 1 * 2048) = c01;
      *(f32x4*)(base + 2 * 2048) = c10;
      *(f32x4*)(base + 3 * 2048) = c11;
      *(f32x4*)(base + 4 * 2048) = c20;
      *(f32x4*)(base + 5 * 2048) = c21;
      *(f32x4*)(base + 6 * 2048) = c30;
      *(f32x4*)(base + 7 * 2048) = c31;
    }
    __syncthreads();

    // ---- epilogue: 2 cells/thread, c-state in registers ----
#pragma unroll
    for (int cc2 = 0; cc2 < 2; ++cc2) {
      const int mloc = mloc0 + cc2 * 32;
      const int mtl = mloc >> 4, qq = (mloc & 15) >> 2, jj = mloc & 3;
      const int lane = qq * 16 + hc;
      float g4[4];
#pragma unroll
      for (int g = 0; g < 4; ++g) {
        const int s = mtl * 2 + (g & 1);
        const int wv = (g >> 1) * 4;
        float sum = 0.f;
#pragma unroll
        for (int k2 = 0; k2 < 4; ++k2)
          sum += red[(size_t)(s * 512 + (wv + k2) * 64 + lane) * 4 + jj];
        g4[g] = sum;
      }
      float gi_ = g4[0] + bs0;
      float gf = g4[1] + bs1;
      float gg = g4[2] + bs2;
      float go = g4[3] + bs3;
      if (t == 0) { gi_ += xg0; gf += xg1; gg += xg2; go += xg3; }
      float cn = sigm(gf) * creg[cc2] + sigm(gi_) * tanh_f(gg);
      creg[cc2] = cn;
      float h = sigm(go) * tanh_f(cn);
      short h16 = f2b(h);
      // agent-scope (sc1) stores: write through to coherence point, no dirty L2
      __hip_atomic_store(dst + hIdx[cc2], h16, __ATOMIC_RELAXED, __HIP_MEMORY_SCOPE_AGENT);
      __hip_atomic_store(hsC + (size_t)tslot * BD * HD + idxA[cc2], h16,
                         __ATOMIC_RELAXED, __HIP_MEMORY_SCOPE_AGENT);
      if (t == TS - 1) {
        __hip_atomic_store(o_h + idxA[cc2], h, __ATOMIC_RELAXED, __HIP_MEMORY_SCOPE_AGENT);
        __hip_atomic_store(o_c + idxA[cc2], cn, __ATOMIC_RELAXED, __HIP_MEMORY_SCOPE_AGENT);
      }
    }
    if (++tslot == CH) tslot = 0;

    // ---- per-by grid barrier: h(t+1) visible (L3) to all same-by blocks ----
    grid_bar(s1, (unsigned)(t + 1), bx);

    // ---- fused out_proj phase every CH steps ----
    if (tslot == 0) {
      if (bx < 2 * CH) {
        const int tloc = bx >> 1, nj = bx & 1;
        const int tglob = t + 1 - CH + tloc;
        const short* hsrc = hsC + (size_t)tloc * BD * HD + (size_t)by * 64 * HD;
        const int amt = w & 3, nfh = w >> 2;
        f32x4 p0 = {}, p1 = {};
#pragma unroll
        for (int cc = 0; cc < 2; ++cc) {
#pragma unroll
          for (int j = 0; j < 8; ++j) {
            const int fi = w * 8 + j;
            const int it = fi >> 2, ml = fi & 3;
            const short* g = hsrc + (size_t)(ml * 16 + r) * HD + (cc * 16 + it) * 32 + q * 8;
            __builtin_amdgcn_global_load_lds((gas_void*)g, (las_void*)(sm + fi * 512), 16, 0, 17);
          }
          asm volatile("s_waitcnt vmcnt(0)" ::: "memory");
          __syncthreads();
#pragma unroll
          for (int itl = 0; itl < 16; ++itl) {
            const short* fb = sm + itl * 2048 + amt * 512 + l * 8;
            s16x8 a = *(const s16x8*)(fb);
            const int kk = (cc * 16 + itl) * 32 + q * 8;
            s16x8 b0 = *(const s16x8*)(outw + (size_t)(nj * 64 + nfh * 32 + r) * HD + kk);
            s16x8 b1 = *(const s16x8*)(outw + (size_t)(nj * 64 + nfh * 32 + 16 + r) * HD + kk);
            p0 = MF(a, b0, p0);
            p1 = MF(a, b1, p1);
          }
          __syncthreads();
        }
#pragma unroll
        for (int f2 = 0; f2 < 2; ++f2) {
          const int col = nj * 64 + nfh * 32 + f2 * 16 + r;
          const float bb = outb[col];
          const f32x4 pa = f2 ? p1 : p0;
#pragma unroll
          for (int j2 = 0; j2 < 4; ++j2) {
            const int brow = by * 64 + amt * 16 + q * 4 + j2;
            __hip_atomic_store(dout + ((size_t)brow * TS + tglob) * OD + col,
                               pa[j2] + bb, __ATOMIC_RELAXED, __HIP_MEMORY_SCOPE_AGENT);
          }
        }
      }
      ++pcnt;
      // nobody overwrites hsC slot 0 before this by-group's phase reads finish
      grid_bar(s2, pcnt, bx);
    }
  }
}

extern "C" void kernel_launch(void* const* d_in, const int* in_sizes, int n_in,
                              void* d_out, int out_size, void* d_ws, size_t ws_size,
                              hipStream_t stream) {
  static const int exp_sizes[26] = {
      131072, 131072, 128, 524288, 1024, 524288, 1024, 131072, 1024,
      4194304, 4194304, 4096, 4096, 131072, 128, 524288, 1024, 1024, 1,
      524288, 1024, 1048576, 1024, 2048, 2, 1};
  if (n_in < 26) return;
  for (int i = 0; i < 26; ++i)
    if (in_sizes[i] != exp_sizes[i]) return;

  const float* enc_out = (const float*)d_in[0];
  const float* enc_hid = (const float*)d_in[1];
  const float* start_tok = (const float*)d_in[2];
  const float* l2h_w = (const float*)d_in[3];
  const float* l2h_b = (const float*)d_in[4];
  const float* l2h2_w = (const float*)d_in[5];
  const float* l2h2_b = (const float*)d_in[6];
  const float* emb_w = (const float*)d_in[7];
  const float* emb_b = (const float*)d_in[8];
  const float* Wih_f = (const float*)d_in[9];
  const float* Whh_f = (const float*)d_in[10];
  const float* bih = (const float*)d_in[11];
  const float* bhh = (const float*)d_in[12];
  const float* outw_f = (const float*)d_in[13];
  const float* outb = (const float*)d_in[14];
  const float* seq_w = (const float*)d_in[15];
  const float* seq_b = (const float*)d_in[16];
  const float* seq2_w = (const float*)d_in[17];
  const float* seq2_b = (const float*)d_in[18];
  const float* mass_w = (const float*)d_in[19];
  const float* mass_b = (const float*)d_in[20];
  const float* mass2_w = (const float*)d_in[21];
  const float* mass2_b = (const float*)d_in[22];
  const float* mass3_w = (const float*)d_in[23];
  const float* mass3_b = (const float*)d_in[24];

  // ---- workspace layout ----
  char* p = (char*)d_ws;
  float* c_buf = (float*)p;  p += (size_t)BD * HD * 4;        // 1 MB
  float* bsum = (float*)p;   p += (size_t)4 * HD * 4;         // 16 KB
  float* xg = (float*)p;     p += (size_t)4 * HD * 4;         // 16 KB
  float* n1 = (float*)p;     p += (size_t)BD * HD * 4;        // 1 MB
  short* m1 = (short*)p;     p += (size_t)BD * HD * 2;        // 512 KB
  short* m2 = (short*)p;     p += (size_t)BD * HD * 2;        // 512 KB
  short* xrow = (short*)p;   p += (size_t)HD * 2;             // 2 KB
  short* hA = (short*)p;     p += (size_t)BD * HD * 2;        // 512 KB
  short* hB = (short*)p;     p += (size_t)BD * HD * 2;        // 512 KB
  short* Wt = (short*)p;     p += (size_t)4 * HD * KC * 2;    // 16 MB
  short* outw = (short*)p;   p += (size_t)OD * HD * 2;        // 256 KB
  unsigned* ctrs = (unsigned*)p; p += 2048;                   // 4 by x 128 words
  short* hsC = (short*)p;    // CH * BD * HD bf16
  size_t fixed_bytes = (size_t)(p - (char*)d_ws);
  const size_t step_bytes = (size_t)BD * HD * 2;
  int CH = 0;
  const int cands[7] = {25, 20, 10, 5, 4, 2, 1};
  for (int ci = 0; ci < 7; ++ci) {
    if (fixed_bytes + (size_t)cands[ci] * step_bytes <= ws_size) { CH = cands[ci]; break; }
  }
  if (CH == 0) return;

  float* dout = (float*)d_out;
  float* o_dec = dout;                       // [B][TS][OD]
  float* o_h = dout + (size_t)BD * TS * OD;  // [1][B][HD]
  float* o_c = o_h + (size_t)BD * HD;        // [1][B][HD]
  float* o_num = o_c + (size_t)BD * HD;      // [B][1]
  float* o_mass = o_num + BD;                // [B][2]

  // prep
  wrep_k<<<4096, 256, 0, stream>>>(Wih_f, Whh_f, Wt);
  cvt8_k<<<OD * HD / 2048, 256, 0, stream>>>(outw_f, outw);
  bsum_k<<<16, 256, 0, stream>>>(bih, bhh, bsum);
  x0_k<<<4, 256, 0, stream>>>(start_tok, emb_w, emb_b, xrow);
  xg_k<<<1024, 256, 0, stream>>>(xrow, Wih_f, xg);
  zero_ctr_k<<<1, 512, 0, stream>>>(ctrs);

  // heads + initial state
  dim3 fcg(16, 4);
  fc_mfma<LATD, false, 2><<<fcg, 256, 0, stream>>>(enc_hid, l2h_w, l2h_b, hA, 0, 0);
  fc_mfma<LATD, false, 0><<<fcg, 256, 0, stream>>>(enc_hid, l2h2_w, l2h2_b, c_buf, 0, 0);
  fc_mfma<LATD, false, 0><<<fcg, 256, 0, stream>>>(enc_out, seq_w, seq_b, n1, 0, 0);
  fc_mfma<LATD, false, 1><<<fcg, 256, 0, stream>>>(enc_out, mass_w, mass_b, m1, HD, 0);
  fc_mfma<HD, true, 1><<<fcg, 256, 0, stream>>>(m1, mass2_w, mass2_b, m2, HD, 0);
  num_k<<<64, 256, 0, stream>>>(n1, seq2_w, seq2_b, o_num);
  mass_k<<<64, 256, 0, stream>>>(m2, mass3_w, mass3_b, o_mass);

  // whole LSTM scan + output projection in ONE persistent launch
  lstm_persist<<<dim3(64, 4), 512, 0, stream>>>(
      hA, hB, c_buf, Wt, bsum, xg, hsC, outw, outb, o_dec, o_h, o_c, ctrs, CH);
}

// Round 6
// 1584.089 us; speedup vs baseline: 1.7379x; 1.7379x over previous
//
#include <hip/hip_runtime.h>

#define BD 256   // batch
#define HD 1024  // hidden
#define KC 2048  // concatenated K = [x | h]
#define LATD 512 // latent
#define OD 128   // output dim
#define TS 100   // seq_len (fixed by problem)

typedef __attribute__((ext_vector_type(8))) short s16x8;
typedef __attribute__((ext_vector_type(4))) float f32x4;

__device__ __forceinline__ float b2f(short s) {
  return __uint_as_float(((unsigned)(unsigned short)s) << 16);
}
__device__ __forceinline__ short f2b(float f) {
  unsigned u = __float_as_uint(f);
  u += 0x7fff + ((u >> 16) & 1);  // RNE
  return (short)(u >> 16);
}
__device__ __forceinline__ float sigm(float x) { return 1.f / (1.f + __expf(-x)); }
__device__ __forceinline__ float tanh_f(float x) { return 1.f - 2.f / (__expf(2.f * x) + 1.f); }

// h-only fragment-major index over kh in [0,1024):
// kc=kh/8, q2=kc/64 (h-quarter), it=(kc/4)%16, qq=kc%4; mt=m/16, r=m%16
// frag (mt,q2,it) base = (mt*32 + q2*16 + it)*512 shorts; lane entry qq*16+r at *8
__device__ __forceinline__ size_t hf_idx(int m, int kh) {
  int kc = kh >> 3;
  int q2 = kc >> 6, it = (kc >> 2) & 15, qq = kc & 3;
  int mt = m >> 4, r = m & 15;
  return (((size_t)(mt * 32 + q2 * 16 + it)) * 64 + qq * 16 + r) * 8 + (kh & 7);
}

// relu on bf16 == signed 16-bit max(s,0) (exact; -0 -> +0)
__device__ __forceinline__ s16x8 relu8(s16x8 v) {
  s16x8 o;
#pragma unroll
  for (int e = 0; e < 8; ++e) o[e] = v[e] > 0 ? v[e] : (short)0;
  return o;
}

// ---------------- one-time prep kernels ----------------

__global__ __launch_bounds__(256) void cvt8_k(const float* __restrict__ in,
                                              short* __restrict__ out) {
  int i = (blockIdx.x * 256 + threadIdx.x) * 8;
  f32x4 a = *(const f32x4*)(in + i), b = *(const f32x4*)(in + i + 4);
  s16x8 o;
#pragma unroll
  for (int e = 0; e < 4; ++e) { o[e] = f2b(a[e]); o[4 + e] = f2b(b[e]); }
  *(s16x8*)(out + i) = o;
}

// Fragment-major weight repack (verified r6):
// chunk i = ((bn*64 + kit)*4 + quad)*16 + lan; bn = g*64+bx; k = kit*32+quad*8
__global__ __launch_bounds__(256) void wrep_k(const float* __restrict__ Wih,
                                              const float* __restrict__ Whh,
                                              short* __restrict__ Wt) {
  int i = blockIdx.x * 256 + threadIdx.x;  // chunk id, < 1048576
  int lan = i & 15, quad = (i >> 4) & 3, kit = (i >> 6) & 63, bn = i >> 12;
  int g = bn >> 6, bx = bn & 63;
  int n = g * HD + bx * 16 + lan;
  int k = kit * 32 + quad * 8;
  const float* src = (k < HD) ? (Wih + (size_t)n * HD + k)
                              : (Whh + (size_t)n * HD + (k - HD));
  f32x4 a = *(const f32x4*)src, b = *(const f32x4*)(src + 4);
  s16x8 o;
#pragma unroll
  for (int e = 0; e < 4; ++e) { o[e] = f2b(a[e]); o[4 + e] = f2b(b[e]); }
  *(s16x8*)(Wt + (size_t)i * 8) = o;
}

__global__ __launch_bounds__(256) void bsum_k(const float* __restrict__ bi,
                                              const float* __restrict__ bh,
                                              float* __restrict__ bs) {
  int i = blockIdx.x * 256 + threadIdx.x;
  bs[i] = bi[i] + bh[i];
}

__global__ __launch_bounds__(256) void x0_k(const float* __restrict__ st,
                                            const float* __restrict__ W,
                                            const float* __restrict__ bias,
                                            short* __restrict__ xrow) {
  int j = blockIdx.x * 256 + threadIdx.x;
  float acc = 0.f;
  for (int k = 0; k < OD; ++k) acc += st[k] * W[j * OD + k];
  acc += bias[j];
  xrow[j] = f2b(acc > 0.f ? acc : 0.f);
}

// xg[j] = sum_k relu(x0)[k] * Wih[j][k]  (step-0 x-contribution, batch-invariant)
__global__ __launch_bounds__(256) void xg_k(const short* __restrict__ xrow,
                                            const float* __restrict__ Wih,
                                            float* __restrict__ xg) {
  int l = threadIdx.x & 63, w = threadIdx.x >> 6;
  int j = blockIdx.x * 4 + w;  // 1024 blocks -> j < 4096
  const float* row = Wih + (size_t)j * HD + l * 16;
  float acc = 0.f;
#pragma unroll
  for (int c = 0; c < 16; ++c) acc += b2f(xrow[l * 16 + c]) * row[c];
  for (int off = 32; off; off >>= 1) acc += __shfl_down(acc, off);
  if (l == 0) xg[j] = acc;
}

__global__ void zero_ctr_k(unsigned* __restrict__ c) { c[threadIdx.x] = 0u; }

// ---------------- head GEMM: out = lrelu(A @ W^T + b), N=1024, M=256 ----------------
// MODE: 0 = fp32 flat [m*1024+col]; 1 = bf16 flat [m*os+oo+col]; 2 = bf16 hf layout
template <int K, bool IN_BF16, int MODE>
__global__ __launch_bounds__(256) void fc_mfma(const void* __restrict__ in_,
                                               const float* __restrict__ W,
                                               const float* __restrict__ bias,
                                               void* __restrict__ out_,
                                               int ostride, int ooff) {
  const int tid = threadIdx.x;
  const int w = tid >> 6, lan = tid & 15, quad = (tid & 63) >> 4;
  const int n0 = blockIdx.x * 64;
  const int m0 = blockIdx.y * 64;
  const int arow = m0 + w * 16 + lan;
  f32x4 acc[4] = {};
  for (int k0 = 0; k0 < K; k0 += 32) {
    const int ka = k0 + quad * 8;
    s16x8 af;
    if (IN_BF16) {
      af = *(const s16x8*)((const short*)in_ + arow * K + ka);
    } else {
      const float* ap = (const float*)in_ + arow * K + ka;
      f32x4 a0 = *(const f32x4*)ap, a1 = *(const f32x4*)(ap + 4);
#pragma unroll
      for (int e = 0; e < 4; ++e) { af[e] = f2b(a0[e]); af[4 + e] = f2b(a1[e]); }
    }
#pragma unroll
    for (int nf = 0; nf < 4; ++nf) {
      const float* bp = W + (n0 + nf * 16 + lan) * K + ka;
      f32x4 b0 = *(const f32x4*)bp, b1 = *(const f32x4*)(bp + 4);
      s16x8 bf;
#pragma unroll
      for (int e = 0; e < 4; ++e) { bf[e] = f2b(b0[e]); bf[4 + e] = f2b(b1[e]); }
      acc[nf] = __builtin_amdgcn_mfma_f32_16x16x32_bf16(af, bf, acc[nf], 0, 0, 0);
    }
  }
#pragma unroll
  for (int nf = 0; nf < 4; ++nf) {
    int col = n0 + nf * 16 + lan;
    float bb = bias[col];
#pragma unroll
    for (int j = 0; j < 4; ++j) {
      int m = m0 + w * 16 + quad * 4 + j;
      float v = acc[nf][j] + bb;
      v = v > 0.f ? v : 0.01f * v;
      if (MODE == 0)
        ((float*)out_)[m * 1024 + col] = v;
      else if (MODE == 1)
        ((short*)out_)[m * ostride + ooff + col] = f2b(v);
      else
        ((short*)out_)[hf_idx(m, col)] = f2b(v);
    }
  }
}

__global__ __launch_bounds__(256) void num_k(const float* __restrict__ n1,
                                             const float* __restrict__ w2,
                                             const float* __restrict__ b2,
                                             float* __restrict__ out) {
  int l = threadIdx.x & 63, w = threadIdx.x >> 6;
  int m = blockIdx.x * 4 + w;
  const float* r = n1 + m * HD + l * 16;
  const float* wv = w2 + l * 16;
  float acc = 0.f;
#pragma unroll
  for (int c = 0; c < 4; ++c) {
    f32x4 a = *(const f32x4*)(r + c * 4), b = *(const f32x4*)(wv + c * 4);
#pragma unroll
    for (int e = 0; e < 4; ++e) acc += a[e] * b[e];
  }
  for (int off = 32; off; off >>= 1) acc += __shfl_down(acc, off);
  if (l == 0) {
    float v = acc + b2[0];
    out[m] = v > 0.f ? v : 0.f;
  }
}

__global__ __launch_bounds__(256) void mass_k(const short* __restrict__ m2,
                                              const float* __restrict__ w3,
                                              const float* __restrict__ b3,
                                              float* __restrict__ out) {
  int l = threadIdx.x & 63, w = threadIdx.x >> 6;
  int m = blockIdx.x * 4 + w;
  const short* r = m2 + m * HD + l * 16;
  s16x8 v0 = *(const s16x8*)r, v1 = *(const s16x8*)(r + 8);
  float z0 = 0.f, z1 = 0.f;
#pragma unroll
  for (int e = 0; e < 8; ++e) {
    float a = b2f(v0[e]), b = b2f(v1[e]);
    z0 += a * w3[l * 16 + e] + b * w3[l * 16 + 8 + e];
    z1 += a * w3[HD + l * 16 + e] + b * w3[HD + l * 16 + 8 + e];
  }
  for (int off = 32; off; off >>= 1) {
    z0 += __shfl_down(z0, off);
    z1 += __shfl_down(z1, off);
  }
  if (l == 0) {
    z0 += b3[0]; z1 += b3[1];
    float mx = fmaxf(z0, z1);
    float e0 = __expf(z0 - mx), e1 = __expf(z1 - mx);
    float s = e0 + e1;
    out[m * 2] = e0 / s;
    out[m * 2 + 1] = e1 / s;
  }
}

// ---------------- persistent LSTM kernel ----------------
// R6: grid (64,4), 1024 threads = 16 waves (4/SIMD — R4 ran 2/SIMD and was
// latency-bound: Mfma 14.6 / VALU 16.4 / Occ 24.7). Wave = (K-quarter w4q,
// gate g); 16 weight frags = 64 pinned VGPRs/thread. Memory semantics are
// R4's proven set: staging via aux=17 (bypass L1+L2, read L3 coherence
// point), h/hsC stores sc1 write-through, NO fences, NO L2 inv (R5's per-step
// buffer_inv was a 2x regression). Staging is 2-phase software-pipelined:
// compute its 0..7 after vmcnt(4) while 4 loads/wave are still in flight.

#define MF(a, b, c) __builtin_amdgcn_mfma_f32_16x16x32_bf16(a, b, c, 0, 0, 0)

typedef __attribute__((address_space(1))) const void gas_void;
typedef __attribute__((address_space(3))) void las_void;

// single-hop barrier: one agent store per block; wave 0 polls all 64 slots.
__device__ __forceinline__ void grid_bar(unsigned* slots, unsigned epoch, int bx) {
  asm volatile("s_waitcnt vmcnt(0)" ::: "memory");  // all sc1 stores acked at L3
  __syncthreads();
  if (threadIdx.x == 0)
    __hip_atomic_store(slots + bx, epoch, __ATOMIC_RELAXED, __HIP_MEMORY_SCOPE_AGENT);
  if (threadIdx.x < 64) {
    while (!__all(__hip_atomic_load(slots + (int)threadIdx.x, __ATOMIC_RELAXED,
                                    __HIP_MEMORY_SCOPE_AGENT) >= epoch))
      __builtin_amdgcn_s_sleep(1);
  }
  __syncthreads();
}

__global__ __launch_bounds__(1024, 4) void lstm_persist(
    short* __restrict__ hA, short* __restrict__ hB, const float* __restrict__ cbuf,
    const short* __restrict__ Wt, const float* __restrict__ bsum,
    const float* __restrict__ xg, short* __restrict__ hsC,
    const short* __restrict__ outw, const float* __restrict__ outb,
    float* __restrict__ dout, float* __restrict__ o_h, float* __restrict__ o_c,
    unsigned* ctr, int CH) {
  __shared__ __align__(16) short sm[65536];  // 2 x 64 KB h-half buffers; red reuses [0,64K)

  const int tid = threadIdx.x;
  const int w = tid >> 6, l = tid & 63;
  const int w4q = w >> 2, g = w & 3;     // wave = (K-quarter, gate)
  const int bx = blockIdx.x, by = blockIdx.y;
  const int q = l >> 4, r = l & 15;
  const int q2 = w4q & 1;                // h data half consumed AND staged
  const int sr8 = (w4q >> 1) * 4 + g;    // stager rank within half [0,8)

  // ---- one-time weight preload: 16 frags = 64 VGPR/thread, pinned ----
  s16x8 W[16];
#pragma unroll
  for (int it = 0; it < 16; ++it)
    W[it] = *(const s16x8*)(Wt + (((size_t)(g * 64 + bx) * 64 + w4q * 16 + it) * 64 + l) * 8);
#pragma unroll
  for (int i = 0; i < 16; ++i) asm volatile("" : "+v"(W[i]));

  // ---- per-thread epilogue constants (1 cell/thread) ----
  const int mloc = tid >> 4, hc = tid & 15;
  const int chh = bx * 16 + hc;
  const float bs0 = bsum[chh], bs1 = bsum[HD + chh];
  const float bs2 = bsum[2 * HD + chh], bs3 = bsum[3 * HD + chh];
  const float xg0 = xg[chh], xg1 = xg[HD + chh];
  const float xg2 = xg[2 * HD + chh], xg3 = xg[3 * HD + chh];
  const int mg = by * 64 + mloc;
  const int idxA = mg * HD + chh;
  const size_t hIdx = hf_idx(mg, chh);
  float creg = cbuf[idxA];  // c-state in a register for all 100 steps
  const int mtlE = mloc >> 4, qqE = (mloc & 15) >> 2, jjE = mloc & 3;
  const int laneE = qqE * 16 + hc;

  float* red = (float*)sm;
  unsigned* s1 = ctr + by * 128;
  unsigned* s2 = s1 + 64;
  int tslot = 0;
  unsigned pcnt = 0;

  for (int t = 0; t < TS; ++t) {
    const short* src = (t & 1) ? hB : hA;
    short* dst = (t & 1) ? hA : hB;

    f32x4 c0 = {}, c1 = {}, c2 = {}, c3 = {};

    // ---- stage 8 frags/wave, it-interleaved: fi = j*8+sr8 -> (it=2j+(w4q>>1), mtl=g) ----
#pragma unroll
    for (int j = 0; j < 8; ++j) {
      const int fi = j * 8 + sr8;
      const int it = fi >> 2, mtl = fi & 3;
      const short* gp = src + ((size_t)((by * 4 + mtl) * 32 + q2 * 16 + it)) * 512 + (size_t)l * 8;
      __builtin_amdgcn_global_load_lds((gas_void*)gp,
                                       (las_void*)(sm + q2 * 32768 + fi * 512), 16, 0, 17);
    }

    const short* cb = sm + q2 * 32768;
    // ---- phase A: its 0..7 ready after first 4 loads/wave land ----
    asm volatile("s_waitcnt vmcnt(4)" ::: "memory");
    __builtin_amdgcn_s_barrier();
    if (t > 0 || w4q >= 2) {
#pragma unroll
      for (int it = 0; it < 8; ++it) {
        const short* fb = cb + it * 2048 + l * 8;
        s16x8 a0 = *(const s16x8*)(fb);
        s16x8 a1 = *(const s16x8*)(fb + 512);
        s16x8 a2 = *(const s16x8*)(fb + 1024);
        s16x8 a3 = *(const s16x8*)(fb + 1536);
        if (w4q < 2) { a0 = relu8(a0); a1 = relu8(a1); a2 = relu8(a2); a3 = relu8(a3); }
        const s16x8 wf = W[it];
        c0 = MF(a0, wf, c0); c1 = MF(a1, wf, c1);
        c2 = MF(a2, wf, c2); c3 = MF(a3, wf, c3);
      }
    }
    // ---- phase B: its 8..15 ----
    asm volatile("s_waitcnt vmcnt(0)" ::: "memory");
    __builtin_amdgcn_s_barrier();
    if (t > 0 || w4q >= 2) {
#pragma unroll
      for (int it = 8; it < 16; ++it) {
        const short* fb = cb + it * 2048 + l * 8;
        s16x8 a0 = *(const s16x8*)(fb);
        s16x8 a1 = *(const s16x8*)(fb + 512);
        s16x8 a2 = *(const s16x8*)(fb + 1024);
        s16x8 a3 = *(const s16x8*)(fb + 1536);
        if (w4q < 2) { a0 = relu8(a0); a1 = relu8(a1); a2 = relu8(a2); a3 = relu8(a3); }
        const s16x8 wf = W[it];
        c0 = MF(a0, wf, c0); c1 = MF(a1, wf, c1);
        c2 = MF(a2, wf, c2); c3 = MF(a3, wf, c3);
      }
    }
    __builtin_amdgcn_s_barrier();  // all LDS reads done before red overwrites [0,64K)

    // ---- partials: slot s = mtl*4 + g, sub-column w4q ----
    *(f32x4*)(red + ((size_t)((0 * 4 + g) * 4 + w4q) * 64 + l) * 4) = c0;
    *(f32x4*)(red + ((size_t)((1 * 4 + g) * 4 + w4q) * 64 + l) * 4) = c1;
    *(f32x4*)(red + ((size_t)((2 * 4 + g) * 4 + w4q) * 64 + l) * 4) = c2;
    *(f32x4*)(red + ((size_t)((3 * 4 + g) * 4 + w4q) * 64 + l) * 4) = c3;
    __syncthreads();

    // ---- epilogue: 1 cell/thread, c-state in register ----
    {
      float g4[4];
#pragma unroll
      for (int gg = 0; gg < 4; ++gg) {
        float sum = 0.f;
#pragma unroll
        for (int k2 = 0; k2 < 4; ++k2)
          sum += red[((size_t)((mtlE * 4 + gg) * 4 + k2) * 64 + laneE) * 4 + jjE];
        g4[gg] = sum;
      }
      float gi_ = g4[0] + bs0;
      float gf = g4[1] + bs1;
      float gg2 = g4[2] + bs2;
      float go = g4[3] + bs3;
      if (t == 0) { gi_ += xg0; gf += xg1; gg2 += xg2; go += xg3; }
      float cn = sigm(gf) * creg + sigm(gi_) * tanh_f(gg2);
      creg = cn;
      float h = sigm(go) * tanh_f(cn);
      short h16 = f2b(h);
      // agent-scope (sc1) write-through: visible at L3 for peers' aux=17 reads
      __hip_atomic_store(dst + hIdx, h16, __ATOMIC_RELAXED, __HIP_MEMORY_SCOPE_AGENT);
      __hip_atomic_store(hsC + (size_t)tslot * BD * HD + idxA, h16,
                         __ATOMIC_RELAXED, __HIP_MEMORY_SCOPE_AGENT);
      if (t == TS - 1) { o_h[idxA] = h; o_c[idxA] = cn; }
    }
    if (++tslot == CH) tslot = 0;

    // ---- per-by grid barrier: h(t+1) visible (L3) to all same-by blocks ----
    grid_bar(s1, (unsigned)(t + 1), bx);

    // ---- fused out_proj phase every CH steps ----
    if (tslot == 0) {
      if (bx < 2 * CH) {
        const int tloc = bx >> 1, nj = bx & 1;
        const int tglob = t + 1 - CH + tloc;
        const short* hsrc = hsC + (size_t)tloc * BD * HD + (size_t)by * 64 * HD;
        const int amt = w & 3, nfh = w >> 2;  // 4 m-tiles x 4 col-16s
        f32x4 p0 = {};
#pragma unroll
        for (int cc = 0; cc < 2; ++cc) {
#pragma unroll
          for (int j = 0; j < 4; ++j) {
            const int fi = w * 4 + j;          // it = w, ml = j
            const short* gp = hsrc + (size_t)(j * 16 + r) * HD + (cc * 16 + w) * 32 + q * 8;
            __builtin_amdgcn_global_load_lds((gas_void*)gp, (las_void*)(sm + fi * 512), 16, 0, 17);
          }
          asm volatile("s_waitcnt vmcnt(0)" ::: "memory");
          __syncthreads();
#pragma unroll
          for (int itl = 0; itl < 16; ++itl) {
            const short* fb = sm + itl * 2048 + amt * 512 + l * 8;
            s16x8 a = *(const s16x8*)(fb);
            const int kk = (cc * 16 + itl) * 32 + q * 8;
            s16x8 b0 = *(const s16x8*)(outw + (size_t)(nj * 64 + nfh * 16 + r) * HD + kk);
            p0 = MF(a, b0, p0);
          }
          __syncthreads();
        }
        {
          const int col = nj * 64 + nfh * 16 + r;
          const float bb = outb[col];
#pragma unroll
          for (int j2 = 0; j2 < 4; ++j2) {
            const int brow = by * 64 + amt * 16 + q * 4 + j2;
            dout[((size_t)brow * TS + tglob) * OD + col] = p0[j2] + bb;
          }
        }
      }
      ++pcnt;
      // nobody overwrites hsC slot 0 before this by-group's phase reads finish
      grid_bar(s2, pcnt, bx);
    }
  }
}

extern "C" void kernel_launch(void* const* d_in, const int* in_sizes, int n_in,
                              void* d_out, int out_size, void* d_ws, size_t ws_size,
                              hipStream_t stream) {
  static const int exp_sizes[26] = {
      131072, 131072, 128, 524288, 1024, 524288, 1024, 131072, 1024,
      4194304, 4194304, 4096, 4096, 131072, 128, 524288, 1024, 1024, 1,
      524288, 1024, 1048576, 1024, 2048, 2, 1};
  if (n_in < 26) return;
  for (int i = 0; i < 26; ++i)
    if (in_sizes[i] != exp_sizes[i]) return;

  const float* enc_out = (const float*)d_in[0];
  const float* enc_hid = (const float*)d_in[1];
  const float* start_tok = (const float*)d_in[2];
  const float* l2h_w = (const float*)d_in[3];
  const float* l2h_b = (const float*)d_in[4];
  const float* l2h2_w = (const float*)d_in[5];
  const float* l2h2_b = (const float*)d_in[6];
  const float* emb_w = (const float*)d_in[7];
  const float* emb_b = (const float*)d_in[8];
  const float* Wih_f = (const float*)d_in[9];
  const float* Whh_f = (const float*)d_in[10];
  const float* bih = (const float*)d_in[11];
  const float* bhh = (const float*)d_in[12];
  const float* outw_f = (const float*)d_in[13];
  const float* outb = (const float*)d_in[14];
  const float* seq_w = (const float*)d_in[15];
  const float* seq_b = (const float*)d_in[16];
  const float* seq2_w = (const float*)d_in[17];
  const float* seq2_b = (const float*)d_in[18];
  const float* mass_w = (const float*)d_in[19];
  const float* mass_b = (const float*)d_in[20];
  const float* mass2_w = (const float*)d_in[21];
  const float* mass2_b = (const float*)d_in[22];
  const float* mass3_w = (const float*)d_in[23];
  const float* mass3_b = (const float*)d_in[24];

  // ---- workspace layout ----
  char* p = (char*)d_ws;
  float* c_buf = (float*)p;  p += (size_t)BD * HD * 4;        // 1 MB
  float* bsum = (float*)p;   p += (size_t)4 * HD * 4;         // 16 KB
  float* xg = (float*)p;     p += (size_t)4 * HD * 4;         // 16 KB
  float* n1 = (float*)p;     p += (size_t)BD * HD * 4;        // 1 MB
  short* m1 = (short*)p;     p += (size_t)BD * HD * 2;        // 512 KB
  short* m2 = (short*)p;     p += (size_t)BD * HD * 2;        // 512 KB
  short* xrow = (short*)p;   p += (size_t)HD * 2;             // 2 KB
  short* hA = (short*)p;     p += (size_t)BD * HD * 2;        // 512 KB
  short* hB = (short*)p;     p += (size_t)BD * HD * 2;        // 512 KB
  short* Wt = (short*)p;     p += (size_t)4 * HD * KC * 2;    // 16 MB
  short* outw = (short*)p;   p += (size_t)OD * HD * 2;        // 256 KB
  unsigned* ctrs = (unsigned*)p; p += 2048;                   // 4 by x 128 words
  short* hsC = (short*)p;    // CH * BD * HD bf16
  size_t fixed_bytes = (size_t)(p - (char*)d_ws);
  const size_t step_bytes = (size_t)BD * HD * 2;
  int CH = 0;
  const int cands[7] = {25, 20, 10, 5, 4, 2, 1};
  for (int ci = 0; ci < 7; ++ci) {
    if (fixed_bytes + (size_t)cands[ci] * step_bytes <= ws_size) { CH = cands[ci]; break; }
  }
  if (CH == 0) return;

  float* dout = (float*)d_out;
  float* o_dec = dout;                       // [B][TS][OD]
  float* o_h = dout + (size_t)BD * TS * OD;  // [1][B][HD]
  float* o_c = o_h + (size_t)BD * HD;        // [1][B][HD]
  float* o_num = o_c + (size_t)BD * HD;      // [B][1]
  float* o_mass = o_num + BD;                // [B][2]

  // prep
  wrep_k<<<4096, 256, 0, stream>>>(Wih_f, Whh_f, Wt);
  cvt8_k<<<OD * HD / 2048, 256, 0, stream>>>(outw_f, outw);
  bsum_k<<<16, 256, 0, stream>>>(bih, bhh, bsum);
  x0_k<<<4, 256, 0, stream>>>(start_tok, emb_w, emb_b, xrow);
  xg_k<<<1024, 256, 0, stream>>>(xrow, Wih_f, xg);
  zero_ctr_k<<<1, 512, 0, stream>>>(ctrs);

  // heads + initial state
  dim3 fcg(16, 4);
  fc_mfma<LATD, false, 2><<<fcg, 256, 0, stream>>>(enc_hid, l2h_w, l2h_b, hA, 0, 0);
  fc_mfma<LATD, false, 0><<<fcg, 256, 0, stream>>>(enc_hid, l2h2_w, l2h2_b, c_buf, 0, 0);
  fc_mfma<LATD, false, 0><<<fcg, 256, 0, stream>>>(enc_out, seq_w, seq_b, n1, 0, 0);
  fc_mfma<LATD, false, 1><<<fcg, 256, 0, stream>>>(enc_out, mass_w, mass_b, m1, HD, 0);
  fc_mfma<HD, true, 1><<<fcg, 256, 0, stream>>>(m1, mass2_w, mass2_b, m2, HD, 0);
  num_k<<<64, 256, 0, stream>>>(n1, seq2_w, seq2_b, o_num);
  mass_k<<<64, 256, 0, stream>>>(m2, mass3_w, mass3_b, o_mass);

  // whole LSTM scan + output projection in ONE persistent launch
  lstm_persist<<<dim3(64, 4), 1024, 0, stream>>>(
      hA, hB, c_buf, Wt, bsum, xg, hsC, outw, outb, o_dec, o_h, o_c, ctrs, CH);
}

// Round 7
// 1507.915 us; speedup vs baseline: 1.8257x; 1.0505x over previous
//
#include <hip/hip_runtime.h>

#define BD 256   // batch
#define HD 1024  // hidden
#define KC 2048  // concatenated K = [x | h]
#define LATD 512 // latent
#define OD 128   // output dim
#define TS 100   // seq_len (fixed by problem)

typedef __attribute__((ext_vector_type(8))) short s16x8;
typedef __attribute__((ext_vector_type(4))) float f32x4;

__device__ __forceinline__ float b2f(short s) {
  return __uint_as_float(((unsigned)(unsigned short)s) << 16);
}
__device__ __forceinline__ short f2b(float f) {
  unsigned u = __float_as_uint(f);
  u += 0x7fff + ((u >> 16) & 1);  // RNE
  return (short)(u >> 16);
}
__device__ __forceinline__ float sigm(float x) { return 1.f / (1.f + __expf(-x)); }
__device__ __forceinline__ float tanh_f(float x) { return 1.f - 2.f / (__expf(2.f * x) + 1.f); }

// h-only fragment-major index over kh in [0,1024):
// kc=kh/8, q2=kc/64 (h-half-of-512), it=(kc/4)%16, qq=kc%4; mt=m/16, r=m%16
// frag (mt,q2,it) base = (mt*32 + q2*16 + it)*512 shorts; lane entry qq*16+r at *8
__device__ __forceinline__ size_t hf_idx(int m, int kh) {
  int kc = kh >> 3;
  int q2 = kc >> 6, it = (kc >> 2) & 15, qq = kc & 3;
  int mt = m >> 4, r = m & 15;
  return (((size_t)(mt * 32 + q2 * 16 + it)) * 64 + qq * 16 + r) * 8 + (kh & 7);
}

// relu on bf16 == signed 16-bit max(s,0) (exact; -0 -> +0)
__device__ __forceinline__ s16x8 relu8(s16x8 v) {
  s16x8 o;
#pragma unroll
  for (int e = 0; e < 8; ++e) o[e] = v[e] > 0 ? v[e] : (short)0;
  return o;
}

// ---------------- one-time prep kernels ----------------

__global__ __launch_bounds__(256) void cvt8_k(const float* __restrict__ in,
                                              short* __restrict__ out) {
  int i = (blockIdx.x * 256 + threadIdx.x) * 8;
  f32x4 a = *(const f32x4*)(in + i), b = *(const f32x4*)(in + i + 4);
  s16x8 o;
#pragma unroll
  for (int e = 0; e < 4; ++e) { o[e] = f2b(a[e]); o[4 + e] = f2b(b[e]); }
  *(s16x8*)(out + i) = o;
}

// Fragment-major weight repack (verified r6):
// chunk i = ((bn*64 + kit)*4 + quad)*16 + lan; bn = g*64+bx; k = kit*32+quad*8
__global__ __launch_bounds__(256) void wrep_k(const float* __restrict__ Wih,
                                              const float* __restrict__ Whh,
                                              short* __restrict__ Wt) {
  int i = blockIdx.x * 256 + threadIdx.x;  // chunk id, < 1048576
  int lan = i & 15, quad = (i >> 4) & 3, kit = (i >> 6) & 63, bn = i >> 12;
  int g = bn >> 6, bx = bn & 63;
  int n = g * HD + bx * 16 + lan;
  int k = kit * 32 + quad * 8;
  const float* src = (k < HD) ? (Wih + (size_t)n * HD + k)
                              : (Whh + (size_t)n * HD + (k - HD));
  f32x4 a = *(const f32x4*)src, b = *(const f32x4*)(src + 4);
  s16x8 o;
#pragma unroll
  for (int e = 0; e < 4; ++e) { o[e] = f2b(a[e]); o[4 + e] = f2b(b[e]); }
  *(s16x8*)(Wt + (size_t)i * 8) = o;
}

__global__ __launch_bounds__(256) void bsum_k(const float* __restrict__ bi,
                                              const float* __restrict__ bh,
                                              float* __restrict__ bs) {
  int i = blockIdx.x * 256 + threadIdx.x;
  bs[i] = bi[i] + bh[i];
}

__global__ __launch_bounds__(256) void x0_k(const float* __restrict__ st,
                                            const float* __restrict__ W,
                                            const float* __restrict__ bias,
                                            short* __restrict__ xrow) {
  int j = blockIdx.x * 256 + threadIdx.x;
  float acc = 0.f;
  for (int k = 0; k < OD; ++k) acc += st[k] * W[j * OD + k];
  acc += bias[j];
  xrow[j] = f2b(acc > 0.f ? acc : 0.f);
}

// xg[j] = sum_k relu(x0)[k] * Wih[j][k]  (step-0 x-contribution, batch-invariant)
__global__ __launch_bounds__(256) void xg_k(const short* __restrict__ xrow,
                                            const float* __restrict__ Wih,
                                            float* __restrict__ xg) {
  int l = threadIdx.x & 63, w = threadIdx.x >> 6;
  int j = blockIdx.x * 4 + w;  // 1024 blocks -> j < 4096
  const float* row = Wih + (size_t)j * HD + l * 16;
  float acc = 0.f;
#pragma unroll
  for (int c = 0; c < 16; ++c) acc += b2f(xrow[l * 16 + c]) * row[c];
  for (int off = 32; off; off >>= 1) acc += __shfl_down(acc, off);
  if (l == 0) xg[j] = acc;
}

__global__ void zero_ctr_k(unsigned* __restrict__ c) { c[threadIdx.x] = 0u; }

// ---------------- head GEMM: out = lrelu(A @ W^T + b), N=1024, M=256 ----------------
// MODE: 0 = fp32 flat [m*1024+col]; 1 = bf16 flat [m*os+oo+col]; 2 = bf16 hf layout
template <int K, bool IN_BF16, int MODE>
__global__ __launch_bounds__(256) void fc_mfma(const void* __restrict__ in_,
                                               const float* __restrict__ W,
                                               const float* __restrict__ bias,
                                               void* __restrict__ out_,
                                               int ostride, int ooff) {
  const int tid = threadIdx.x;
  const int w = tid >> 6, lan = tid & 15, quad = (tid & 63) >> 4;
  const int n0 = blockIdx.x * 64;
  const int m0 = blockIdx.y * 64;
  const int arow = m0 + w * 16 + lan;
  f32x4 acc[4] = {};
  for (int k0 = 0; k0 < K; k0 += 32) {
    const int ka = k0 + quad * 8;
    s16x8 af;
    if (IN_BF16) {
      af = *(const s16x8*)((const short*)in_ + arow * K + ka);
    } else {
      const float* ap = (const float*)in_ + arow * K + ka;
      f32x4 a0 = *(const f32x4*)ap, a1 = *(const f32x4*)(ap + 4);
#pragma unroll
      for (int e = 0; e < 4; ++e) { af[e] = f2b(a0[e]); af[4 + e] = f2b(a1[e]); }
    }
#pragma unroll
    for (int nf = 0; nf < 4; ++nf) {
      const float* bp = W + (n0 + nf * 16 + lan) * K + ka;
      f32x4 b0 = *(const f32x4*)bp, b1 = *(const f32x4*)(bp + 4);
      s16x8 bf;
#pragma unroll
      for (int e = 0; e < 4; ++e) { bf[e] = f2b(b0[e]); bf[4 + e] = f2b(b1[e]); }
      acc[nf] = __builtin_amdgcn_mfma_f32_16x16x32_bf16(af, bf, acc[nf], 0, 0, 0);
    }
  }
#pragma unroll
  for (int nf = 0; nf < 4; ++nf) {
    int col = n0 + nf * 16 + lan;
    float bb = bias[col];
#pragma unroll
    for (int j = 0; j < 4; ++j) {
      int m = m0 + w * 16 + quad * 4 + j;
      float v = acc[nf][j] + bb;
      v = v > 0.f ? v : 0.01f * v;
      if (MODE == 0)
        ((float*)out_)[m * 1024 + col] = v;
      else if (MODE == 1)
        ((short*)out_)[m * ostride + ooff + col] = f2b(v);
      else
        ((short*)out_)[hf_idx(m, col)] = f2b(v);
    }
  }
}

__global__ __launch_bounds__(256) void num_k(const float* __restrict__ n1,
                                             const float* __restrict__ w2,
                                             const float* __restrict__ b2,
                                             float* __restrict__ out) {
  int l = threadIdx.x & 63, w = threadIdx.x >> 6;
  int m = blockIdx.x * 4 + w;
  const float* r = n1 + m * HD + l * 16;
  const float* wv = w2 + l * 16;
  float acc = 0.f;
#pragma unroll
  for (int c = 0; c < 4; ++c) {
    f32x4 a = *(const f32x4*)(r + c * 4), b = *(const f32x4*)(wv + c * 4);
#pragma unroll
    for (int e = 0; e < 4; ++e) acc += a[e] * b[e];
  }
  for (int off = 32; off; off >>= 1) acc += __shfl_down(acc, off);
  if (l == 0) {
    float v = acc + b2[0];
    out[m] = v > 0.f ? v : 0.f;
  }
}

__global__ __launch_bounds__(256) void mass_k(const short* __restrict__ m2,
                                              const float* __restrict__ w3,
                                              const float* __restrict__ b3,
                                              float* __restrict__ out) {
  int l = threadIdx.x & 63, w = threadIdx.x >> 6;
  int m = blockIdx.x * 4 + w;
  const short* r = m2 + m * HD + l * 16;
  s16x8 v0 = *(const s16x8*)r, v1 = *(const s16x8*)(r + 8);
  float z0 = 0.f, z1 = 0.f;
#pragma unroll
  for (int e = 0; e < 8; ++e) {
    float a = b2f(v0[e]), b = b2f(v1[e]);
    z0 += a * w3[l * 16 + e] + b * w3[l * 16 + 8 + e];
    z1 += a * w3[HD + l * 16 + e] + b * w3[HD + l * 16 + 8 + e];
  }
  for (int off = 32; off; off >>= 1) {
    z0 += __shfl_down(z0, off);
    z1 += __shfl_down(z1, off);
  }
  if (l == 0) {
    z0 += b3[0]; z1 += b3[1];
    float mx = fmaxf(z0, z1);
    float e0 = __expf(z0 - mx), e1 = __expf(z1 - mx);
    float s = e0 + e1;
    out[m * 2] = e0 / s;
    out[m * 2 + 1] = e1 / s;
  }
}

// ---------------- persistent LSTM kernel ----------------
// R7: h exchange through a RING of CH+1 buffers so addresses are only reused
// every CH+1 steps -> main-loop staging can be L2-CACHEABLE (aux=0). The 64x
// by-group broadcast is then served by each XCD's L2 (R4/R6 were L3-BW-bound
// at ~12 us/step with bypass reads). One fence(acquire,agent) per CH steps at
// the out_proj rendezvous drops potentially-stale clean lines before any slot
// reuse (any CH-step window contains a rendezvous). ALL global stores remain
// sc1 write-through -> L2 never dirty -> the inv can never lose data.
// XCD swizzle: by-group g lives on XCDs {2g,2g+1} (32 blocks each) so each
// XCD pulls only its own group's 128 KB/step from L3 and shares it 32-way.

#define MF(a, b, c) __builtin_amdgcn_mfma_f32_16x16x32_bf16(a, b, c, 0, 0, 0)

typedef __attribute__((address_space(1))) const void gas_void;
typedef __attribute__((address_space(3))) void las_void;

// single-hop barrier: one agent store per block; wave 0 polls all 64 slots.
__device__ __forceinline__ void grid_bar(unsigned* slots, unsigned epoch, int bx) {
  asm volatile("s_waitcnt vmcnt(0)" ::: "memory");  // all sc1 stores acked at L3
  __syncthreads();
  if (threadIdx.x == 0)
    __hip_atomic_store(slots + bx, epoch, __ATOMIC_RELAXED, __HIP_MEMORY_SCOPE_AGENT);
  if (threadIdx.x < 64) {
    while (!__all(__hip_atomic_load(slots + (int)threadIdx.x, __ATOMIC_RELAXED,
                                    __HIP_MEMORY_SCOPE_AGENT) >= epoch))
      __builtin_amdgcn_s_sleep(1);
  }
  __syncthreads();
}

__global__ __launch_bounds__(1024, 4) void lstm_persist(
    short* __restrict__ ring, const float* __restrict__ cbuf,
    const short* __restrict__ Wt, const float* __restrict__ bsum,
    const float* __restrict__ xg,
    const short* __restrict__ outw, const float* __restrict__ outb,
    float* __restrict__ dout, float* __restrict__ o_h, float* __restrict__ o_c,
    unsigned* ctr, int CH, int R) {
  __shared__ __align__(16) short sm[65536];  // 2 x 64 KB h-half buffers; red reuses [0,64K)

  // XCD swizzle (id%8 round-robin assumption; perf-only if mapping differs)
  const int lid = blockIdx.x;
  const int xcd = lid & 7;
  const int by = xcd >> 1;
  const int bx = (lid >> 3) * 2 + (xcd & 1);

  const int tid = threadIdx.x;
  const int w = tid >> 6, l = tid & 63;
  const int w4q = w >> 2, g = w & 3;     // wave = (K-quarter, gate)
  const int q = l >> 4, r = l & 15;
  const int q2 = w4q & 1;                // h data half consumed AND staged
  const int sr8 = (w4q >> 1) * 4 + g;    // stager rank within half [0,8)

  // ---- one-time weight preload: 16 frags = 64 VGPR/thread, pinned ----
  s16x8 W[16];
#pragma unroll
  for (int it = 0; it < 16; ++it)
    W[it] = *(const s16x8*)(Wt + (((size_t)(g * 64 + bx) * 64 + w4q * 16 + it) * 64 + l) * 8);
#pragma unroll
  for (int i = 0; i < 16; ++i) asm volatile("" : "+v"(W[i]));

  // ---- per-thread epilogue constants (1 cell/thread) ----
  const int mloc = tid >> 4, hc = tid & 15;
  const int chh = bx * 16 + hc;
  const float bs0 = bsum[chh], bs1 = bsum[HD + chh];
  const float bs2 = bsum[2 * HD + chh], bs3 = bsum[3 * HD + chh];
  const float xg0 = xg[chh], xg1 = xg[HD + chh];
  const float xg2 = xg[2 * HD + chh], xg3 = xg[3 * HD + chh];
  const int mg = by * 64 + mloc;
  const int idxA = mg * HD + chh;
  const size_t hIdx = hf_idx(mg, chh);
  float creg = cbuf[idxA];  // c-state in a register for all 100 steps
  const int mtlE = mloc >> 4, qqE = (mloc & 15) >> 2, jjE = mloc & 3;
  const int laneE = qqE * 16 + hc;

  const size_t BUFSZ = (size_t)BD * HD;
  float* red = (float*)sm;
  unsigned* s1 = ctr + by * 128;
  unsigned* s2 = s1 + 64;
  int tslot = 0;
  unsigned pcnt = 0;

  for (int t = 0; t < TS; ++t) {
    const short* src = ring + (size_t)(t % R) * BUFSZ;
    short* dst = ring + (size_t)((t + 1) % R) * BUFSZ;

    f32x4 c0 = {}, c1 = {}, c2 = {}, c3 = {};

    // ---- stage 8 frags/wave (CACHEABLE: L2 serves the 32-way XCD broadcast) ----
#pragma unroll
    for (int j = 0; j < 8; ++j) {
      const int fi = j * 8 + sr8;
      const int it = fi >> 2, mtl = fi & 3;
      const short* gp = src + ((size_t)((by * 4 + mtl) * 32 + q2 * 16 + it)) * 512 + (size_t)l * 8;
      __builtin_amdgcn_global_load_lds((gas_void*)gp,
                                       (las_void*)(sm + q2 * 32768 + fi * 512), 16, 0, 0);
    }

    const short* cb = sm + q2 * 32768;
    // ---- phase A: its 0..7 ready after first 4 loads/wave land ----
    asm volatile("s_waitcnt vmcnt(4)" ::: "memory");
    __builtin_amdgcn_s_barrier();
    if (t > 0 || w4q >= 2) {
#pragma unroll
      for (int it = 0; it < 8; ++it) {
        const short* fb = cb + it * 2048 + l * 8;
        s16x8 a0 = *(const s16x8*)(fb);
        s16x8 a1 = *(const s16x8*)(fb + 512);
        s16x8 a2 = *(const s16x8*)(fb + 1024);
        s16x8 a3 = *(const s16x8*)(fb + 1536);
        if (w4q < 2) { a0 = relu8(a0); a1 = relu8(a1); a2 = relu8(a2); a3 = relu8(a3); }
        const s16x8 wf = W[it];
        c0 = MF(a0, wf, c0); c1 = MF(a1, wf, c1);
        c2 = MF(a2, wf, c2); c3 = MF(a3, wf, c3);
      }
    }
    // ---- phase B: its 8..15 ----
    asm volatile("s_waitcnt vmcnt(0)" ::: "memory");
    __builtin_amdgcn_s_barrier();
    if (t > 0 || w4q >= 2) {
#pragma unroll
      for (int it = 8; it < 16; ++it) {
        const short* fb = cb + it * 2048 + l * 8;
        s16x8 a0 = *(const s16x8*)(fb);
        s16x8 a1 = *(const s16x8*)(fb + 512);
        s16x8 a2 = *(const s16x8*)(fb + 1024);
        s16x8 a3 = *(const s16x8*)(fb + 1536);
        if (w4q < 2) { a0 = relu8(a0); a1 = relu8(a1); a2 = relu8(a2); a3 = relu8(a3); }
        const s16x8 wf = W[it];
        c0 = MF(a0, wf, c0); c1 = MF(a1, wf, c1);
        c2 = MF(a2, wf, c2); c3 = MF(a3, wf, c3);
      }
    }
    __builtin_amdgcn_s_barrier();  // all LDS reads done before red overwrites [0,64K)

    // ---- partials: slot s = mtl*4 + g, sub-column w4q ----
    *(f32x4*)(red + ((size_t)((0 * 4 + g) * 4 + w4q) * 64 + l) * 4) = c0;
    *(f32x4*)(red + ((size_t)((1 * 4 + g) * 4 + w4q) * 64 + l) * 4) = c1;
    *(f32x4*)(red + ((size_t)((2 * 4 + g) * 4 + w4q) * 64 + l) * 4) = c2;
    *(f32x4*)(red + ((size_t)((3 * 4 + g) * 4 + w4q) * 64 + l) * 4) = c3;
    __syncthreads();

    // ---- epilogue: 1 cell/thread, c-state in register ----
    {
      float g4[4];
#pragma unroll
      for (int gg = 0; gg < 4; ++gg) {
        float sum = 0.f;
#pragma unroll
        for (int k2 = 0; k2 < 4; ++k2)
          sum += red[((size_t)((mtlE * 4 + gg) * 4 + k2) * 64 + laneE) * 4 + jjE];
        g4[gg] = sum;
      }
      float gi_ = g4[0] + bs0;
      float gf = g4[1] + bs1;
      float gg2 = g4[2] + bs2;
      float go = g4[3] + bs3;
      if (t == 0) { gi_ += xg0; gf += xg1; gg2 += xg2; go += xg3; }
      float cn = sigm(gf) * creg + sigm(gi_) * tanh_f(gg2);
      creg = cn;
      float h = sigm(go) * tanh_f(cn);
      short h16 = f2b(h);
      // sc1 write-through: L3 holds truth; no dirty L2 anywhere in this kernel
      __hip_atomic_store(dst + hIdx, h16, __ATOMIC_RELAXED, __HIP_MEMORY_SCOPE_AGENT);
      if (t == TS - 1) {
        __hip_atomic_store(o_h + idxA, h, __ATOMIC_RELAXED, __HIP_MEMORY_SCOPE_AGENT);
        __hip_atomic_store(o_c + idxA, cn, __ATOMIC_RELAXED, __HIP_MEMORY_SCOPE_AGENT);
      }
    }
    if (++tslot == CH) tslot = 0;

    // ---- per-by grid barrier: h(t+1) visible (L3 + maybe fresh L2) ----
    grid_bar(s1, (unsigned)(t + 1), bx);

    // ---- rendezvous every CH steps: inv stale clean lines + fused out_proj ----
    if (tslot == 0) {
      // drop possibly-stale clean L2 lines before any ring-slot reuse.
      // Safe: sc1-everywhere -> no dirty lines to lose.
      __builtin_amdgcn_fence(__ATOMIC_ACQUIRE, "agent");
      if (bx < 2 * CH) {
        const int tloc = bx >> 1, nj = bx & 1;
        const int tglob = t + 1 - CH + tloc;
        // h produced by step tglob lives in ring slot (tglob+1)%R, hf layout
        const short* hsrc = ring + (size_t)((tglob + 1) % R) * BUFSZ;
        const int amt = w & 3, nfh = w >> 2;  // 4 m-tiles x 4 col-16s
        f32x4 p0 = {};
#pragma unroll
        for (int cc = 0; cc < 2; ++cc) {
#pragma unroll
          for (int j = 0; j < 4; ++j) {
            const int fi = w * 4 + j;          // it = w, ml = j
            const short* gp = hsrc + ((size_t)((by * 4 + j) * 32 + cc * 16 + w)) * 512 + (size_t)l * 8;
            __builtin_amdgcn_global_load_lds((gas_void*)gp, (las_void*)(sm + fi * 512), 16, 0, 17);
          }
          asm volatile("s_waitcnt vmcnt(0)" ::: "memory");
          __syncthreads();
#pragma unroll
          for (int itl = 0; itl < 16; ++itl) {
            const short* fb = sm + itl * 2048 + amt * 512 + l * 8;
            s16x8 a = *(const s16x8*)(fb);
            const int kk = (cc * 16 + itl) * 32 + q * 8;
            s16x8 b0 = *(const s16x8*)(outw + (size_t)(nj * 64 + nfh * 16 + r) * HD + kk);
            p0 = MF(a, b0, p0);
          }
          __syncthreads();
        }
        {
          const int col = nj * 64 + nfh * 16 + r;
          const float bb = outb[col];
#pragma unroll
          for (int j2 = 0; j2 < 4; ++j2) {
            const int brow = by * 64 + amt * 16 + q * 4 + j2;
            __hip_atomic_store(dout + ((size_t)brow * TS + tglob) * OD + col,
                               p0[j2] + bb, __ATOMIC_RELAXED, __HIP_MEMORY_SCOPE_AGENT);
          }
        }
      }
      ++pcnt;
      // nobody overwrites the chunk's ring slots before phase reads finish
      grid_bar(s2, pcnt, bx);
    }
  }
}

extern "C" void kernel_launch(void* const* d_in, const int* in_sizes, int n_in,
                              void* d_out, int out_size, void* d_ws, size_t ws_size,
                              hipStream_t stream) {
  static const int exp_sizes[26] = {
      131072, 131072, 128, 524288, 1024, 524288, 1024, 131072, 1024,
      4194304, 4194304, 4096, 4096, 131072, 128, 524288, 1024, 1024, 1,
      524288, 1024, 1048576, 1024, 2048, 2, 1};
  if (n_in < 26) return;
  for (int i = 0; i < 26; ++i)
    if (in_sizes[i] != exp_sizes[i]) return;

  const float* enc_out = (const float*)d_in[0];
  const float* enc_hid = (const float*)d_in[1];
  const float* start_tok = (const float*)d_in[2];
  const float* l2h_w = (const float*)d_in[3];
  const float* l2h_b = (const float*)d_in[4];
  const float* l2h2_w = (const float*)d_in[5];
  const float* l2h2_b = (const float*)d_in[6];
  const float* emb_w = (const float*)d_in[7];
  const float* emb_b = (const float*)d_in[8];
  const float* Wih_f = (const float*)d_in[9];
  const float* Whh_f = (const float*)d_in[10];
  const float* bih = (const float*)d_in[11];
  const float* bhh = (const float*)d_in[12];
  const float* outw_f = (const float*)d_in[13];
  const float* outb = (const float*)d_in[14];
  const float* seq_w = (const float*)d_in[15];
  const float* seq_b = (const float*)d_in[16];
  const float* seq2_w = (const float*)d_in[17];
  const float* seq2_b = (const float*)d_in[18];
  const float* mass_w = (const float*)d_in[19];
  const float* mass_b = (const float*)d_in[20];
  const float* mass2_w = (const float*)d_in[21];
  const float* mass2_b = (const float*)d_in[22];
  const float* mass3_w = (const float*)d_in[23];
  const float* mass3_b = (const float*)d_in[24];

  // ---- workspace layout (ring sized by CH ladder) ----
  char* p = (char*)d_ws;
  float* c_buf = (float*)p;  p += (size_t)BD * HD * 4;        // 1 MB
  float* bsum = (float*)p;   p += (size_t)4 * HD * 4;         // 16 KB
  float* xg = (float*)p;     p += (size_t)4 * HD * 4;         // 16 KB
  float* n1 = (float*)p;     p += (size_t)BD * HD * 4;        // 1 MB
  short* m1 = (short*)p;     p += (size_t)BD * HD * 2;        // 512 KB
  short* m2 = (short*)p;     p += (size_t)BD * HD * 2;        // 512 KB
  short* xrow = (short*)p;   p += (size_t)HD * 2;             // 2 KB
  short* Wt = (short*)p;     p += (size_t)4 * HD * KC * 2;    // 16 MB
  short* outw = (short*)p;   p += (size_t)OD * HD * 2;        // 256 KB
  unsigned* ctrs = (unsigned*)p; p += 2048;                   // 4 by x 128 words
  short* ring = (short*)p;   // (CH+1) x BD*HD bf16
  size_t fixed_bytes = (size_t)(p - (char*)d_ws);
  const size_t step_bytes = (size_t)BD * HD * 2;
  int CH = 0;
  const int cands[7] = {25, 20, 10, 5, 4, 2, 1};
  for (int ci = 0; ci < 7; ++ci) {
    if (fixed_bytes + (size_t)(cands[ci] + 1) * step_bytes <= ws_size) { CH = cands[ci]; break; }
  }
  if (CH == 0) return;

  float* dout = (float*)d_out;
  float* o_dec = dout;                       // [B][TS][OD]
  float* o_h = dout + (size_t)BD * TS * OD;  // [1][B][HD]
  float* o_c = o_h + (size_t)BD * HD;        // [1][B][HD]
  float* o_num = o_c + (size_t)BD * HD;      // [B][1]
  float* o_mass = o_num + BD;                // [B][2]

  // prep
  wrep_k<<<4096, 256, 0, stream>>>(Wih_f, Whh_f, Wt);
  cvt8_k<<<OD * HD / 2048, 256, 0, stream>>>(outw_f, outw);
  bsum_k<<<16, 256, 0, stream>>>(bih, bhh, bsum);
  x0_k<<<4, 256, 0, stream>>>(start_tok, emb_w, emb_b, xrow);
  xg_k<<<1024, 256, 0, stream>>>(xrow, Wih_f, xg);
  zero_ctr_k<<<1, 512, 0, stream>>>(ctrs);

  // heads + initial state (h0 -> ring slot 0)
  dim3 fcg(16, 4);
  fc_mfma<LATD, false, 2><<<fcg, 256, 0, stream>>>(enc_hid, l2h_w, l2h_b, ring, 0, 0);
  fc_mfma<LATD, false, 0><<<fcg, 256, 0, stream>>>(enc_hid, l2h2_w, l2h2_b, c_buf, 0, 0);
  fc_mfma<LATD, false, 0><<<fcg, 256, 0, stream>>>(enc_out, seq_w, seq_b, n1, 0, 0);
  fc_mfma<LATD, false, 1><<<fcg, 256, 0, stream>>>(enc_out, mass_w, mass_b, m1, HD, 0);
  fc_mfma<HD, true, 1><<<fcg, 256, 0, stream>>>(m1, mass2_w, mass2_b, m2, HD, 0);
  num_k<<<64, 256, 0, stream>>>(n1, seq2_w, seq2_b, o_num);
  mass_k<<<64, 256, 0, stream>>>(m2, mass3_w, mass3_b, o_mass);

  // whole LSTM scan + output projection in ONE persistent launch
  lstm_persist<<<256, 1024, 0, stream>>>(
      ring, c_buf, Wt, bsum, xg, outw, outb, o_dec, o_h, o_c, ctrs, CH, CH + 1);
}

// Round 8
// 1176.816 us; speedup vs baseline: 2.3393x; 1.2814x over previous
//
#include <hip/hip_runtime.h>

#define BD 256   // batch
#define HD 1024  // hidden
#define KC 2048  // concatenated K = [x | h]
#define LATD 512 // latent
#define OD 128   // output dim
#define TS 100   // seq_len (fixed by problem)

typedef __attribute__((ext_vector_type(8))) short s16x8;
typedef __attribute__((ext_vector_type(4))) float f32x4;

__device__ __forceinline__ float b2f(short s) {
  return __uint_as_float(((unsigned)(unsigned short)s) << 16);
}
__device__ __forceinline__ short f2b(float f) {
  unsigned u = __float_as_uint(f);
  u += 0x7fff + ((u >> 16) & 1);  // RNE
  return (short)(u >> 16);
}
__device__ __forceinline__ float sigm(float x) { return 1.f / (1.f + __expf(-x)); }
__device__ __forceinline__ float tanh_f(float x) { return 1.f - 2.f / (__expf(2.f * x) + 1.f); }

// h-only fragment-major index over kh in [0,1024):
// kc=kh/8, q2=kc/64 (h-half sel), it=(kc/4)%16, qq=kc%4; mt=m/16, r=m%16
// frag (mt,q2,it) base = (mt*32 + q2*16 + it)*512 shorts; lane entry qq*16+r at *8
__device__ __forceinline__ size_t hf_idx(int m, int kh) {
  int kc = kh >> 3;
  int q2 = kc >> 6, it = (kc >> 2) & 15, qq = kc & 3;
  int mt = m >> 4, r = m & 15;
  return (((size_t)(mt * 32 + q2 * 16 + it)) * 64 + qq * 16 + r) * 8 + (kh & 7);
}

// relu on bf16 == signed 16-bit max(s,0) (exact; -0 -> +0)
__device__ __forceinline__ s16x8 relu8(s16x8 v) {
  s16x8 o;
#pragma unroll
  for (int e = 0; e < 8; ++e) o[e] = v[e] > 0 ? v[e] : (short)0;
  return o;
}

// ---------------- one-time prep kernels ----------------

// Fragment-major weight repack (verified r6):
// chunk i = ((bn*64 + kit)*4 + quad)*16 + lan; bn = g*64+bx; k = kit*32+quad*8
__global__ __launch_bounds__(256) void wrep_k(const float* __restrict__ Wih,
                                              const float* __restrict__ Whh,
                                              short* __restrict__ Wt) {
  int i = blockIdx.x * 256 + threadIdx.x;  // chunk id, < 1048576
  int lan = i & 15, quad = (i >> 4) & 3, kit = (i >> 6) & 63, bn = i >> 12;
  int g = bn >> 6, bx = bn & 63;
  int n = g * HD + bx * 16 + lan;
  int k = kit * 32 + quad * 8;
  const float* src = (k < HD) ? (Wih + (size_t)n * HD + k)
                              : (Whh + (size_t)n * HD + (k - HD));
  f32x4 a = *(const f32x4*)src, b = *(const f32x4*)(src + 4);
  s16x8 o;
#pragma unroll
  for (int e = 0; e < 4; ++e) { o[e] = f2b(a[e]); o[4 + e] = f2b(b[e]); }
  *(s16x8*)(Wt + (size_t)i * 8) = o;
}

// fused small prep: bsum (blocks 0..15), x0 (16..19), ctr zero (20), cvt8 outw (21..84)
__global__ __launch_bounds__(256) void prep_small(
    const float* __restrict__ bi, const float* __restrict__ bh, float* __restrict__ bs,
    const float* __restrict__ st, const float* __restrict__ embW,
    const float* __restrict__ embB, short* __restrict__ xrow,
    unsigned* __restrict__ ctrs,
    const float* __restrict__ outw_f, short* __restrict__ outw) {
  const int b = blockIdx.x, tid = threadIdx.x;
  if (b < 16) {
    int i = b * 256 + tid;
    bs[i] = bi[i] + bh[i];
  } else if (b < 20) {
    int j = (b - 16) * 256 + tid;
    float acc = 0.f;
    for (int k = 0; k < OD; ++k) acc += st[k] * embW[j * OD + k];
    acc += embB[j];
    xrow[j] = f2b(acc > 0.f ? acc : 0.f);
  } else if (b == 20) {
#pragma unroll
    for (int e = 0; e < 4; ++e) ctrs[tid * 4 + e] = 0u;
  } else {
    int i = ((b - 21) * 256 + tid) * 8;
    f32x4 a = *(const f32x4*)(outw_f + i), c = *(const f32x4*)(outw_f + i + 4);
    s16x8 o;
#pragma unroll
    for (int e = 0; e < 4; ++e) { o[e] = f2b(a[e]); o[4 + e] = f2b(c[e]); }
    *(s16x8*)(outw + i) = o;
  }
}

// xg[j] = sum_k relu(x0)[k] * Wih[j][k]  (step-0 x-contribution, batch-invariant)
__global__ __launch_bounds__(256) void xg_k(const short* __restrict__ xrow,
                                            const float* __restrict__ Wih,
                                            float* __restrict__ xg) {
  int l = threadIdx.x & 63, w = threadIdx.x >> 6;
  int j = blockIdx.x * 4 + w;  // 1024 blocks -> j < 4096
  const float* row = Wih + (size_t)j * HD + l * 16;
  float acc = 0.f;
#pragma unroll
  for (int c = 0; c < 16; ++c) acc += b2f(xrow[l * 16 + c]) * row[c];
  for (int off = 32; off; off >>= 1) acc += __shfl_down(acc, off);
  if (l == 0) xg[j] = acc;
}

// ---------------- head GEMMs ----------------
// merged 4 heads (all K=512, fp32 in), z selects op:
// z0: l2h -> ring slot0 (hf, lrelu->bf16); z1: l2h2 -> cbuf fp32; z2: seq -> n1 fp32;
// z3: mass -> m1 bf16 flat
__global__ __launch_bounds__(256) void fc_heads(
    const float* __restrict__ enc_hid, const float* __restrict__ enc_out,
    const float* __restrict__ w0, const float* __restrict__ b0,
    const float* __restrict__ w1, const float* __restrict__ b1,
    const float* __restrict__ w2, const float* __restrict__ b2,
    const float* __restrict__ w3, const float* __restrict__ b3,
    short* __restrict__ ring, float* __restrict__ cbuf,
    float* __restrict__ n1, short* __restrict__ m1) {
  const int z = blockIdx.z;
  const float* in_ = (z <= 1) ? enc_hid : enc_out;
  const float* W = (z == 0) ? w0 : (z == 1) ? w1 : (z == 2) ? w2 : w3;
  const float* bias = (z == 0) ? b0 : (z == 1) ? b1 : (z == 2) ? b2 : b3;
  const int tid = threadIdx.x;
  const int w = tid >> 6, lan = tid & 15, quad = (tid & 63) >> 4;
  const int n0 = blockIdx.x * 64;
  const int m0 = blockIdx.y * 64;
  const int arow = m0 + w * 16 + lan;
  f32x4 acc[4] = {};
  for (int k0 = 0; k0 < LATD; k0 += 32) {
    const int ka = k0 + quad * 8;
    s16x8 af;
    const float* ap = in_ + (size_t)arow * LATD + ka;
    f32x4 a0 = *(const f32x4*)ap, a1 = *(const f32x4*)(ap + 4);
#pragma unroll
    for (int e = 0; e < 4; ++e) { af[e] = f2b(a0[e]); af[4 + e] = f2b(a1[e]); }
#pragma unroll
    for (int nf = 0; nf < 4; ++nf) {
      const float* bp = W + (size_t)(n0 + nf * 16 + lan) * LATD + ka;
      f32x4 b0v = *(const f32x4*)bp, b1v = *(const f32x4*)(bp + 4);
      s16x8 bf;
#pragma unroll
      for (int e = 0; e < 4; ++e) { bf[e] = f2b(b0v[e]); bf[4 + e] = f2b(b1v[e]); }
      acc[nf] = __builtin_amdgcn_mfma_f32_16x16x32_bf16(af, bf, acc[nf], 0, 0, 0);
    }
  }
#pragma unroll
  for (int nf = 0; nf < 4; ++nf) {
    int col = n0 + nf * 16 + lan;
    float bb = bias[col];
#pragma unroll
    for (int j = 0; j < 4; ++j) {
      int m = m0 + w * 16 + quad * 4 + j;
      float v = acc[nf][j] + bb;
      v = v > 0.f ? v : 0.01f * v;
      if (z == 0)      ring[hf_idx(m, col)] = f2b(v);
      else if (z == 1) cbuf[m * HD + col] = v;
      else if (z == 2) n1[m * HD + col] = v;
      else             m1[m * HD + col] = f2b(v);
    }
  }
}

// mass2: K=1024 bf16-in -> bf16 flat
__global__ __launch_bounds__(256) void fc_mass2(const short* __restrict__ in_,
                                                const float* __restrict__ W,
                                                const float* __restrict__ bias,
                                                short* __restrict__ out_) {
  const int tid = threadIdx.x;
  const int w = tid >> 6, lan = tid & 15, quad = (tid & 63) >> 4;
  const int n0 = blockIdx.x * 64;
  const int m0 = blockIdx.y * 64;
  const int arow = m0 + w * 16 + lan;
  f32x4 acc[4] = {};
  for (int k0 = 0; k0 < HD; k0 += 32) {
    const int ka = k0 + quad * 8;
    s16x8 af = *(const s16x8*)(in_ + (size_t)arow * HD + ka);
#pragma unroll
    for (int nf = 0; nf < 4; ++nf) {
      const float* bp = W + (size_t)(n0 + nf * 16 + lan) * HD + ka;
      f32x4 b0v = *(const f32x4*)bp, b1v = *(const f32x4*)(bp + 4);
      s16x8 bf;
#pragma unroll
      for (int e = 0; e < 4; ++e) { bf[e] = f2b(b0v[e]); bf[4 + e] = f2b(b1v[e]); }
      acc[nf] = __builtin_amdgcn_mfma_f32_16x16x32_bf16(af, bf, acc[nf], 0, 0, 0);
    }
  }
#pragma unroll
  for (int nf = 0; nf < 4; ++nf) {
    int col = n0 + nf * 16 + lan;
    float bb = bias[col];
#pragma unroll
    for (int j = 0; j < 4; ++j) {
      int m = m0 + w * 16 + quad * 4 + j;
      float v = acc[nf][j] + bb;
      v = v > 0.f ? v : 0.01f * v;
      out_[(size_t)m * HD + col] = f2b(v);
    }
  }
}

// merged tails: blocks 0..63 num head, 64..127 mass softmax
__global__ __launch_bounds__(256) void num_mass_k(
    const float* __restrict__ n1, const float* __restrict__ w2, const float* __restrict__ b2,
    float* __restrict__ onum, const short* __restrict__ m2,
    const float* __restrict__ w3, const float* __restrict__ b3, float* __restrict__ omass) {
  int l = threadIdx.x & 63, w = threadIdx.x >> 6;
  if (blockIdx.x < 64) {
    int m = blockIdx.x * 4 + w;
    const float* r = n1 + (size_t)m * HD + l * 16;
    const float* wv = w2 + l * 16;
    float acc = 0.f;
#pragma unroll
    for (int c = 0; c < 4; ++c) {
      f32x4 a = *(const f32x4*)(r + c * 4), b = *(const f32x4*)(wv + c * 4);
#pragma unroll
      for (int e = 0; e < 4; ++e) acc += a[e] * b[e];
    }
    for (int off = 32; off; off >>= 1) acc += __shfl_down(acc, off);
    if (l == 0) {
      float v = acc + b2[0];
      onum[m] = v > 0.f ? v : 0.f;
    }
  } else {
    int m = (blockIdx.x - 64) * 4 + w;
    const short* r = m2 + (size_t)m * HD + l * 16;
    s16x8 v0 = *(const s16x8*)r, v1 = *(const s16x8*)(r + 8);
    float z0 = 0.f, z1 = 0.f;
#pragma unroll
    for (int e = 0; e < 8; ++e) {
      float a = b2f(v0[e]), b = b2f(v1[e]);
      z0 += a * w3[l * 16 + e] + b * w3[l * 16 + 8 + e];
      z1 += a * w3[HD + l * 16 + e] + b * w3[HD + l * 16 + 8 + e];
    }
    for (int off = 32; off; off >>= 1) {
      z0 += __shfl_down(z0, off);
      z1 += __shfl_down(z1, off);
    }
    if (l == 0) {
      z0 += b3[0]; z1 += b3[1];
      float mx = fmaxf(z0, z1);
      float e0 = __expf(z0 - mx), e1 = __expf(z1 - mx);
      float s = e0 + e1;
      omass[m * 2] = e0 / s;
      omass[m * 2 + 1] = e1 / s;
    }
  }
}

// ---------------- persistent LSTM kernel ----------------
// R8: R4's measured-best 8-wave core (512 thr, gate-pair waves, 512 KB LDS reads,
// W[32]=128 pinned VGPR, aux=17 staging, sc1 h-stores, NO fences) + ring exchange
// (subsumes hsC) + TREE barrier: only block bx==0 sweeps the 64 arrival slots;
// all others store-once then poll a single release flag with ONE lane. This kills
// the 256-block x 64-lane poll storm on the slot lines (R3-R7's hidden cost:
// pollers contended with the arrival stores at L3; invisible in FETCH_SIZE).

#define MF(a, b, c) __builtin_amdgcn_mfma_f32_16x16x32_bf16(a, b, c, 0, 0, 0)

typedef __attribute__((address_space(1))) const void gas_void;
typedef __attribute__((address_space(3))) void las_void;

__device__ __forceinline__ void grid_bar(unsigned* slots, unsigned* flag,
                                         unsigned epoch, int bx) {
  asm volatile("s_waitcnt vmcnt(0)" ::: "memory");  // all sc1 stores acked at L3
  __syncthreads();
  const int tid = threadIdx.x;
  if (tid == 0)
    __hip_atomic_store(slots + bx, epoch, __ATOMIC_RELAXED, __HIP_MEMORY_SCOPE_AGENT);
  if (bx == 0) {
    if (tid < 64) {
      while (!__all(__hip_atomic_load(slots + tid, __ATOMIC_RELAXED,
                                      __HIP_MEMORY_SCOPE_AGENT) >= epoch))
        __builtin_amdgcn_s_sleep(2);
      if (tid == 0)
        __hip_atomic_store(flag, epoch, __ATOMIC_RELAXED, __HIP_MEMORY_SCOPE_AGENT);
    }
  } else if (tid == 0) {
    while (__hip_atomic_load(flag, __ATOMIC_RELAXED, __HIP_MEMORY_SCOPE_AGENT) < epoch)
      __builtin_amdgcn_s_sleep(2);
  }
  __syncthreads();
}

__global__ __launch_bounds__(512, 2) void lstm_persist(
    short* __restrict__ ring, const float* __restrict__ cbuf,
    const short* __restrict__ Wt, const float* __restrict__ bsum,
    const float* __restrict__ xg,
    const short* __restrict__ outw, const float* __restrict__ outb,
    float* __restrict__ dout, float* __restrict__ o_h, float* __restrict__ o_c,
    unsigned* ctr, int CH, int R) {
  __shared__ __align__(16) short sm[65536];  // 2 x 64 KB h-half buffers; red reuses [0,64K)

  const int tid = threadIdx.x;
  const int w = tid >> 6, l = tid & 63;
  const int w4 = w & 3, gp = w >> 2;   // wave = (K-quarter, gate-pair)
  const int bx = blockIdx.x, by = blockIdx.y;
  const int q = l >> 4, r = l & 15;
  const int q2 = w4 & 1;               // h-half this wave consumes
  const int sr = (w4 >> 1) + 2 * gp;   // stager rank within half [0,4)

  // ---- one-time weight preload: kq = w4, 32 frags = 128 VGPR/thread ----
  s16x8 W[32];
#pragma unroll
  for (int it = 0; it < 16; ++it)
#pragma unroll
    for (int gi = 0; gi < 2; ++gi) {
      const int g = gp * 2 + gi;
      W[it * 2 + gi] =
          *(const s16x8*)(Wt + (((size_t)(g * 64 + bx) * 64 + w4 * 16 + it) * 64 + l) * 8);
    }
  // pin: opaque to the register allocator -> no remat/re-stream from L2
#pragma unroll
  for (int i = 0; i < 32; ++i) asm volatile("" : "+v"(W[i]));

  // ---- per-thread epilogue constants ----
  const int mloc0 = tid >> 4, hc = tid & 15;
  const int chh = bx * 16 + hc;
  const float bs0 = bsum[chh], bs1 = bsum[HD + chh];
  const float bs2 = bsum[2 * HD + chh], bs3 = bsum[3 * HD + chh];
  const float xg0 = xg[chh], xg1 = xg[HD + chh];
  const float xg2 = xg[2 * HD + chh], xg3 = xg[3 * HD + chh];
  int idxA[2];
  size_t hIdx[2];
  float creg[2];
#pragma unroll
  for (int cc2 = 0; cc2 < 2; ++cc2) {
    const int mg = by * 64 + mloc0 + cc2 * 32;
    idxA[cc2] = mg * HD + chh;
    hIdx[cc2] = hf_idx(mg, chh);
    creg[cc2] = cbuf[idxA[cc2]];  // c-state in registers for all 100 steps
  }

  const size_t BUFSZ = (size_t)BD * HD;
  float* red = (float*)sm;
  unsigned* cbase = ctr + by * 256;
  unsigned* s1 = cbase;            // 64 arrival slots (lines 0..3)
  unsigned* f1 = cbase + 80;       // release flag (line 5)
  unsigned* s2 = cbase + 128;      // 64 arrival slots (lines 8..11)
  unsigned* f2g = cbase + 208;     // release flag (line 13)
  int tslot = 0;
  unsigned pcnt = 0;

  for (int t = 0; t < TS; ++t) {
    const short* src = ring + (size_t)(t % R) * BUFSZ;
    short* dst = ring + (size_t)((t + 1) % R) * BUFSZ;

    f32x4 c00 = {}, c01 = {}, c10 = {}, c11 = {};
    f32x4 c20 = {}, c21 = {}, c30 = {}, c31 = {};

    // ---- stage this wave's 16 frags of h-half q2 (aux=17: read at L3) ----
#pragma unroll
    for (int j = 0; j < 16; ++j) {
      const int fi = sr * 16 + j;            // it = fi>>2, mtl = fi&3
      const int it = fi >> 2, mtl = fi & 3;
      const short* g = src + ((size_t)((by * 4 + mtl) * 32 + q2 * 16 + it)) * 512 + (size_t)l * 8;
      __builtin_amdgcn_global_load_lds((gas_void*)g,
                                       (las_void*)(sm + q2 * 32768 + fi * 512), 16, 0, 17);
    }
    asm volatile("s_waitcnt vmcnt(0)" ::: "memory");
    __builtin_amdgcn_s_barrier();

    // ---- 128 MFMA/wave on own half; x-waves apply in-register relu ----
    if (t > 0 || w4 >= 2) {
      const short* cb = sm + q2 * 32768;
#pragma unroll
      for (int it = 0; it < 16; ++it) {
        const short* fb = cb + it * 2048 + l * 8;
        s16x8 a0 = *(const s16x8*)(fb);
        s16x8 a1 = *(const s16x8*)(fb + 512);
        s16x8 a2 = *(const s16x8*)(fb + 1024);
        s16x8 a3 = *(const s16x8*)(fb + 1536);
        if (w4 < 2) { a0 = relu8(a0); a1 = relu8(a1); a2 = relu8(a2); a3 = relu8(a3); }
        const s16x8 w0 = W[it * 2], w1 = W[it * 2 + 1];
        c00 = MF(a0, w0, c00); c01 = MF(a0, w1, c01);
        c10 = MF(a1, w0, c10); c11 = MF(a1, w1, c11);
        c20 = MF(a2, w0, c20); c21 = MF(a2, w1, c21);
        c30 = MF(a3, w0, c30); c31 = MF(a3, w1, c31);
      }
    }
    __builtin_amdgcn_s_barrier();  // all LDS reads done before red overwrites [0,64K)

    // ---- partials to LDS: slot s = mtl*2+gi at float ((s*512 + w*64 + l)*4) ----
    {
      float* base = red + (size_t)(w * 64 + l) * 4;
      *(f32x4*)(base + 0 * 2048) = c00;
      *(f32x4*)(base + 1 * 2048) = c01;
      *(f32x4*)(base + 2 * 2048) = c10;
      *(f32x4*)(base + 3 * 2048) = c11;
      *(f32x4*)(base + 4 * 2048) = c20;
      *(f32x4*)(base + 5 * 2048) = c21;
      *(f32x4*)(base + 6 * 2048) = c30;
      *(f32x4*)(base + 7 * 2048) = c31;
    }
    __syncthreads();

    // ---- epilogue: 2 cells/thread, c-state in registers ----
#pragma unroll
    for (int cc2 = 0; cc2 < 2; ++cc2) {
      const int mloc = mloc0 + cc2 * 32;
      const int mtl = mloc >> 4, qq = (mloc & 15) >> 2, jj = mloc & 3;
      const int lane = qq * 16 + hc;
      float g4[4];
#pragma unroll
      for (int g = 0; g < 4; ++g) {
        const int s = mtl * 2 + (g & 1);
        const int wv = (g >> 1) * 4;
        float sum = 0.f;
#pragma unroll
        for (int k2 = 0; k2 < 4; ++k2)
          sum += red[(size_t)(s * 512 + (wv + k2) * 64 + lane) * 4 + jj];
        g4[g] = sum;
      }
      float gi_ = g4[0] + bs0;
      float gf = g4[1] + bs1;
      float gg = g4[2] + bs2;
      float go = g4[3] + bs3;
      if (t == 0) { gi_ += xg0; gf += xg1; gg += xg2; go += xg3; }
      float cn = sigm(gf) * creg[cc2] + sigm(gi_) * tanh_f(gg);
      creg[cc2] = cn;
      float h = sigm(go) * tanh_f(cn);
      short h16 = f2b(h);
      // sc1 write-through: visible at L3 for peers' aux=17 reads
      __hip_atomic_store(dst + hIdx[cc2], h16, __ATOMIC_RELAXED, __HIP_MEMORY_SCOPE_AGENT);
      if (t == TS - 1) { o_h[idxA[cc2]] = h; o_c[idxA[cc2]] = cn; }
    }
    if (++tslot == CH) tslot = 0;

    // ---- per-by grid barrier: h(t+1) visible (L3) to all same-by blocks ----
    grid_bar(s1, f1, (unsigned)(t + 1), bx);

    // ---- fused out_proj phase every CH steps ----
    if (tslot == 0) {
      if (bx < 2 * CH) {
        const int tloc = bx >> 1, nj = bx & 1;
        const int tglob = t + 1 - CH + tloc;
        // h of step tglob lives in ring slot (tglob+1)%R, hf frag layout
        const short* hsrc = ring + (size_t)((tglob + 1) % R) * BUFSZ;
        const int amt = w & 3, nfh = w >> 2;
        f32x4 p0 = {}, p1 = {};
#pragma unroll
        for (int cc = 0; cc < 2; ++cc) {
#pragma unroll
          for (int j = 0; j < 8; ++j) {
            const int fi = w * 8 + j;
            const int it = fi >> 2, ml = fi & 3;
            const short* g = hsrc + ((size_t)((by * 4 + ml) * 32 + cc * 16 + it)) * 512 + (size_t)l * 8;
            __builtin_amdgcn_global_load_lds((gas_void*)g, (las_void*)(sm + fi * 512), 16, 0, 17);
          }
          asm volatile("s_waitcnt vmcnt(0)" ::: "memory");
          __syncthreads();
#pragma unroll
          for (int itl = 0; itl < 16; ++itl) {
            const short* fb = sm + itl * 2048 + amt * 512 + l * 8;
            s16x8 a = *(const s16x8*)(fb);
            const int kk = (cc * 16 + itl) * 32 + q * 8;
            s16x8 b0 = *(const s16x8*)(outw + (size_t)(nj * 64 + nfh * 32 + r) * HD + kk);
            s16x8 b1 = *(const s16x8*)(outw + (size_t)(nj * 64 + nfh * 32 + 16 + r) * HD + kk);
            p0 = MF(a, b0, p0);
            p1 = MF(a, b1, p1);
          }
          __syncthreads();
        }
#pragma unroll
        for (int f2 = 0; f2 < 2; ++f2) {
          const int col = nj * 64 + nfh * 32 + f2 * 16 + r;
          const float bb = outb[col];
          const f32x4 pa = f2 ? p1 : p0;
#pragma unroll
          for (int j2 = 0; j2 < 4; ++j2) {
            const int brow = by * 64 + amt * 16 + q * 4 + j2;
            dout[((size_t)brow * TS + tglob) * OD + col] = pa[j2] + bb;
          }
        }
      }
      ++pcnt;
      // nobody overwrites the chunk's ring slots before phase reads finish
      grid_bar(s2, f2g, pcnt, bx);
    }
  }
}

extern "C" void kernel_launch(void* const* d_in, const int* in_sizes, int n_in,
                              void* d_out, int out_size, void* d_ws, size_t ws_size,
                              hipStream_t stream) {
  static const int exp_sizes[26] = {
      131072, 131072, 128, 524288, 1024, 524288, 1024, 131072, 1024,
      4194304, 4194304, 4096, 4096, 131072, 128, 524288, 1024, 1024, 1,
      524288, 1024, 1048576, 1024, 2048, 2, 1};
  if (n_in < 26) return;
  for (int i = 0; i < 26; ++i)
    if (in_sizes[i] != exp_sizes[i]) return;

  const float* enc_out = (const float*)d_in[0];
  const float* enc_hid = (const float*)d_in[1];
  const float* start_tok = (const float*)d_in[2];
  const float* l2h_w = (const float*)d_in[3];
  const float* l2h_b = (const float*)d_in[4];
  const float* l2h2_w = (const float*)d_in[5];
  const float* l2h2_b = (const float*)d_in[6];
  const float* emb_w = (const float*)d_in[7];
  const float* emb_b = (const float*)d_in[8];
  const float* Wih_f = (const float*)d_in[9];
  const float* Whh_f = (const float*)d_in[10];
  const float* bih = (const float*)d_in[11];
  const float* bhh = (const float*)d_in[12];
  const float* outw_f = (const float*)d_in[13];
  const float* outb = (const float*)d_in[14];
  const float* seq_w = (const float*)d_in[15];
  const float* seq_b = (const float*)d_in[16];
  const float* seq2_w = (const float*)d_in[17];
  const float* seq2_b = (const float*)d_in[18];
  const float* mass_w = (const float*)d_in[19];
  const float* mass_b = (const float*)d_in[20];
  const float* mass2_w = (const float*)d_in[21];
  const float* mass2_b = (const float*)d_in[22];
  const float* mass3_w = (const float*)d_in[23];
  const float* mass3_b = (const float*)d_in[24];

  // ---- workspace layout ----
  char* p = (char*)d_ws;
  float* c_buf = (float*)p;  p += (size_t)BD * HD * 4;        // 1 MB
  float* bsum = (float*)p;   p += (size_t)4 * HD * 4;         // 16 KB
  float* xg = (float*)p;     p += (size_t)4 * HD * 4;         // 16 KB
  float* n1 = (float*)p;     p += (size_t)BD * HD * 4;        // 1 MB
  short* m1 = (short*)p;     p += (size_t)BD * HD * 2;        // 512 KB
  short* m2 = (short*)p;     p += (size_t)BD * HD * 2;        // 512 KB
  short* xrow = (short*)p;   p += (size_t)HD * 2;             // 2 KB
  short* Wt = (short*)p;     p += (size_t)4 * HD * KC * 2;    // 16 MB
  short* outw = (short*)p;   p += (size_t)OD * HD * 2;        // 256 KB
  unsigned* ctrs = (unsigned*)p; p += 4096;                   // 4 by x 256 words
  short* ring = (short*)p;   // (CH+1) x BD*HD bf16
  size_t fixed_bytes = (size_t)(p - (char*)d_ws);
  const size_t step_bytes = (size_t)BD * HD * 2;
  int CH = 0;
  const int cands[7] = {25, 20, 10, 5, 4, 2, 1};
  for (int ci = 0; ci < 7; ++ci) {
    if (fixed_bytes + (size_t)(cands[ci] + 1) * step_bytes <= ws_size) { CH = cands[ci]; break; }
  }
  if (CH == 0) return;

  float* dout = (float*)d_out;
  float* o_dec = dout;                       // [B][TS][OD]
  float* o_h = dout + (size_t)BD * TS * OD;  // [1][B][HD]
  float* o_c = o_h + (size_t)BD * HD;        // [1][B][HD]
  float* o_num = o_c + (size_t)BD * HD;      // [B][1]
  float* o_mass = o_num + BD;                // [B][2]

  // prep (fused: 4 launches)
  wrep_k<<<4096, 256, 0, stream>>>(Wih_f, Whh_f, Wt);
  prep_small<<<85, 256, 0, stream>>>(bih, bhh, bsum, start_tok, emb_w, emb_b,
                                     xrow, ctrs, outw_f, outw);
  xg_k<<<1024, 256, 0, stream>>>(xrow, Wih_f, xg);

  // heads (merged) + mass2 + tails
  fc_heads<<<dim3(16, 4, 4), 256, 0, stream>>>(
      enc_hid, enc_out, l2h_w, l2h_b, l2h2_w, l2h2_b, seq_w, seq_b, mass_w, mass_b,
      ring, c_buf, n1, m1);
  fc_mass2<<<dim3(16, 4), 256, 0, stream>>>(m1, mass2_w, mass2_b, m2);
  num_mass_k<<<128, 256, 0, stream>>>(n1, seq2_w, seq2_b, o_num, m2, mass3_w, mass3_b, o_mass);

  // whole LSTM scan + output projection in ONE persistent launch
  lstm_persist<<<dim3(64, 4), 512, 0, stream>>>(
      ring, c_buf, Wt, bsum, xg, outw, outb, o_dec, o_h, o_c, ctrs, CH, CH + 1);
}